// Round 4
// baseline (289.506 us; speedup 1.0000x reference)
//
#include <hip/hip_runtime.h>
#include <hip/hip_bf16.h>

#define BB 4
#define LL 2048
#define DD 512
#define DKK 256

typedef __bf16 bf16;
typedef __bf16 bf16x4 __attribute__((ext_vector_type(4)));
typedef __bf16 bf16x8 __attribute__((ext_vector_type(8)));
typedef float f32x4 __attribute__((ext_vector_type(4)));

__device__ __forceinline__ void async_ld16(const bf16* g, bf16* l) {
    __builtin_amdgcn_global_load_lds(
        (const __attribute__((address_space(1))) void*)g,
        (__attribute__((address_space(3))) void*)l, 16, 0, 0);
}

// fused bf16 conversion of the three [B,L,D] activations (one launch)
__global__ void conv3_f32_bf16(const float* __restrict__ a, const float* __restrict__ bq,
                               const float* __restrict__ c,
                               bf16* __restrict__ oa, bf16* __restrict__ ob,
                               bf16* __restrict__ oc, int n4) {
    const float* in = (blockIdx.y == 0) ? a : (blockIdx.y == 1) ? bq : c;
    bf16* out = (blockIdx.y == 0) ? oa : (blockIdx.y == 1) ? ob : oc;
    int i = blockIdx.x * 256 + threadIdx.x;
    if (i < n4) {
        f32x4 v = *(const f32x4*)(in + (size_t)i * 4);
        bf16x4 o;
        #pragma unroll
        for (int j = 0; j < 4; ++j) o[j] = (bf16)v[j];
        *(bf16x4*)(out + (size_t)i * 4) = o;
    }
}

__global__ void conv_f32_bf16v(const float* __restrict__ in, bf16* __restrict__ out, int n4) {
    int i = blockIdx.x * 256 + threadIdx.x;
    if (i < n4) {
        f32x4 v = *(const f32x4*)(in + (size_t)i * 4);
        bf16x4 o;
        #pragma unroll
        for (int j = 0; j < 4; ++j) o[j] = (bf16)v[j];
        *(bf16x4*)(out + (size_t)i * 4) = o;
    }
}

__global__ void transpose_f32_bf16(const float* __restrict__ in, bf16* __restrict__ out,
                                   int R, int C) {
    int idx = blockIdx.x * 256 + threadIdx.x;
    if (idx < R * C) {
        int r = idx / C, c = idx % C;
        out[(size_t)c * R + r] = (bf16)in[idx];
    }
}

// 64x64-tile bf16 transpose: in [R][C] -> out [C][R], coalesced both sides.
__global__ void transpose_bf16_tile(const bf16* __restrict__ in, bf16* __restrict__ out,
                                    int R, int C) {
    __shared__ bf16 t[64][72];
    int tcx = C >> 6;
    int bx = blockIdx.x % tcx, by = blockIdx.x / tcx;
    int r = threadIdx.x >> 2, cc = (threadIdx.x & 3) * 16;
    const bf16* src = in + (size_t)(by * 64 + r) * C + bx * 64 + cc;
    bf16x8 v0 = *(const bf16x8*)src;
    bf16x8 v1 = *(const bf16x8*)(src + 8);
    #pragma unroll
    for (int u = 0; u < 8; ++u) { t[cc + u][r] = v0[u]; t[cc + 8 + u][r] = v1[u]; }
    __syncthreads();
    bf16* dst = out + (size_t)(bx * 64 + r) * R + by * 64 + cc;
    *(bf16x8*)dst = *(const bf16x8*)&t[r][cc];
    *(bf16x8*)(dst + 8) = *(const bf16x8*)&t[r][cc + 8];
}

// Unified bf16 GEMM, m97-style: C[m][n] = sum_k A[m][k]*B[n][k].  128x128 tile,
// 4 waves (each 64x64 = 4x4 acc).  A and B staged direct-to-LDS via
// global_load_lds(16B) with parity-rotation swizzle.  bStride lets blockIdx.y
// batch over different B operands (Q+K fused launch).
// SKEW=1: scatter-store into skewed Srel layout.
template <int SKEW>
__launch_bounds__(256, 2)
__global__ void gemm128(const bf16* __restrict__ A, const bf16* __restrict__ B,
                        bf16* __restrict__ C, int N, int K,
                        long aStride, long bStride, long cStride)
{
    __shared__ bf16 Als[128 * 32];
    __shared__ bf16 Bls[128 * 32];

    int tid  = threadIdx.x;
    int lane = tid & 63;
    int wid  = tid >> 6;
    int l15  = lane & 15;
    int quad = lane >> 4;
    int nb = N >> 7;
    int gx = blockIdx.x % nb;
    int gy = blockIdx.x / nb;

    const bf16* Ab = A + (size_t)blockIdx.y * aStride + (size_t)gy * 128 * K;
    const bf16* Bb = B + (size_t)blockIdx.y * bStride + (size_t)gx * 128 * K;

    int rl = lane >> 2;     // staging: row within 16-row inst
    int sl = lane & 3;      // staging: slot
    int half = wid & 1;     // waves 0/2: rows 0-63; waves 1/3: rows 64-127
    const bf16* gsrc = (wid < 2) ? Ab : Bb;
    bf16* ldst = (wid < 2) ? Als : Bls;

    f32x4 acc[4][4];
    #pragma unroll
    for (int i = 0; i < 4; ++i)
        #pragma unroll
        for (int j = 0; j < 4; ++j) acc[i][j] = 0;

    for (int k0 = 0; k0 < K; k0 += 32) {
        #pragma unroll
        for (int u = 0; u < 4; ++u) {
            int inst = half * 4 + u;
            int row  = inst * 16 + rl;
            int c    = (sl - (row >> 1)) & 3;
            async_ld16(gsrc + (size_t)row * K + k0 + c * 8, ldst + inst * 512);
        }
        __syncthreads();   // drains vmcnt(0): staging complete
        bf16x8 fA[4], fB[4];
        #pragma unroll
        for (int rt = 0; rt < 4; ++rt) {
            int row = (wid & 1) * 64 + rt * 16 + l15;
            int s   = (quad + (row >> 1)) & 3;
            fA[rt] = *(const bf16x8*)&Als[row * 32 + s * 8];
        }
        #pragma unroll
        for (int ct = 0; ct < 4; ++ct) {
            int col = (wid >> 1) * 64 + ct * 16 + l15;
            int s   = (quad + (col >> 1)) & 3;
            fB[ct] = *(const bf16x8*)&Bls[col * 32 + s * 8];
        }
        #pragma unroll
        for (int rt = 0; rt < 4; ++rt)
            #pragma unroll
            for (int ct = 0; ct < 4; ++ct)
                acc[rt][ct] = __builtin_amdgcn_mfma_f32_16x16x32_bf16(
                                  fA[rt], fB[ct], acc[rt][ct], 0, 0, 0);
        __syncthreads();   // LDS reuse guard
    }

    bf16* Cb = C + (size_t)blockIdx.y * cStride;
    int m0 = gy * 128 + (wid & 1) * 64;
    int n0 = gx * 128 + (wid >> 1) * 64;
    if (!SKEW) {
        #pragma unroll
        for (int rt = 0; rt < 4; ++rt)
            #pragma unroll
            for (int ct = 0; ct < 4; ++ct)
                #pragma unroll
                for (int r = 0; r < 4; ++r) {
                    int m = m0 + rt * 16 + quad * 4 + r;
                    int n = n0 + ct * 16 + l15;
                    Cb[(size_t)m * N + n] = (bf16)acc[rt][ct][r];
                }
    } else {
        #pragma unroll
        for (int rt = 0; rt < 4; ++rt)
            #pragma unroll
            for (int ct = 0; ct < 4; ++ct)
                #pragma unroll
                for (int r = 0; r < 4; ++r) {
                    int row = m0 + rt * 16 + quad * 4 + r;
                    int c   = n0 + ct * 16 + l15;
                    bool lower = (c >= LL - 1 - row);
                    int dr = lower ? row : row - 1;
                    int dc = lower ? c - (LL - 1 - row) : c + row + 1;
                    if (lower || row >= 1)
                        Cb[(size_t)dr * LL + dc] = (bf16)acc[rt][ct][r];
                }
    }
}

// Fused attention, R11: direct-to-register K/V/Srel loads (no K/V LDS -- they
// are L2-resident via XCD pinning, same bytes as staging moved through L2),
// now FULLY SOFTWARE-PIPELINED so no load sits on the critical path:
//   kf(i+1):  issued at top of softmax(i)  -> window = softmax+b3+PV+loopback
//   vf(i):    issued after QK(i)'s MFMAs   -> window = b2+softmax+b3
//   srel(i+1):issued with vf(i)            -> window > full iteration
// All loads are compiler-tracked register loads (precise vmcnt insertion at
// use); the two raw lgkm-only s_barriers do NOT drain vmcnt, so prefetches
// stay in flight across them.  Last-iter prefetches use a clamped base
// (tile 0) instead of a branch so SIWaitcnt tracking stays precise.
// R10's failure mode (kf load->use in same phase, ~300cy exposed/iter) is
// eliminated.  Hazards: Ss RAW=b2, WAR=b3; Ps/aSt RAW=b3, WAR=next b2.
__launch_bounds__(256, 2)
__global__ void attn_kernel(const bf16* __restrict__ Qw, const bf16* __restrict__ Kw,
                            const bf16* __restrict__ Vt, const bf16* __restrict__ Srel,
                            float* __restrict__ out)
{
    __shared__ float Ss[32][68];
    __shared__ bf16  Ps[32][72];
    __shared__ float mSt[32], lSt[32], aSt[32];

    int tid  = threadIdx.x;
    int lane = tid & 63;
    int wid  = tid >> 6;
    int l15  = lane & 15;
    int quad = lane >> 4;

    int xcd = blockIdx.x & 7;          // XCD = blockIdx % 8 (round-robin dispatch)
    int b   = xcd >> 1;
    int dh  = xcd & 1;
    int i0  = (blockIdx.x >> 3) * 32;

    const bf16* Qb = Qw + (size_t)b * LL * DKK;
    const bf16* Kb = Kw + (size_t)b * LL * DKK;
    const bf16* Sb = Srel + (size_t)b * LL * LL;
    const bf16* Vb = Vt + (size_t)(dh * 256) * (BB * LL) + (size_t)b * LL;

    bf16x8 Qreg[2][8];
    #pragma unroll
    for (int rt = 0; rt < 2; ++rt)
        #pragma unroll
        for (int ks = 0; ks < 8; ++ks)
            Qreg[rt][ks] = *(const bf16x8*)(Qb + (size_t)(i0 + rt * 16 + l15) * DKK
                                            + ks * 32 + quad * 8);

    if (tid < 32) { mSt[tid] = -1e30f; lSt[tid] = 0.f; }

    f32x4 accO[2][4];
    #pragma unroll
    for (int rt = 0; rt < 2; ++rt)
        #pragma unroll
        for (int nt = 0; nt < 4; ++nt) accO[rt][nt] = 0;

    int srow = i0 + (tid >> 3), ssg = tid & 7;
    int jrow = wid * 16 + l15;

    // ---- prologue: prefetch kf(0) and srel(0) (flight spans to first use) ----
    bf16x8 kf[8];
    #pragma unroll
    for (int ks = 0; ks < 8; ++ks)
        kf[ks] = *(const bf16x8*)(Kb + (size_t)jrow * DKK + ks * 32 + quad * 8);
    bf16x8 srelCur = *(const bf16x8*)(Sb + (size_t)srow * LL + ssg * 8);

    for (int j0 = 0; j0 < LL; j0 += 64) {
        int jn = j0 + 64;
        bool notlast = (jn < LL);
        int jc = notlast ? jn : 0;     // clamped next-tile base (keeps last-iter
                                       // prefetches unconditional: precise waitcnt)

        // ===== QK phase (kf prefetched one phase-group ago) =====
        f32x4 s0 = 0, s1 = 0;
        __builtin_amdgcn_s_setprio(1);
        #pragma unroll
        for (int ks = 0; ks < 8; ++ks) {
            s0 = __builtin_amdgcn_mfma_f32_16x16x32_bf16(Qreg[0][ks], kf[ks], s0, 0, 0, 0);
            s1 = __builtin_amdgcn_mfma_f32_16x16x32_bf16(Qreg[1][ks], kf[ks], s1, 0, 0, 0);
        }
        __builtin_amdgcn_s_setprio(0);
        #pragma unroll
        for (int r = 0; r < 4; ++r) {
            Ss[quad * 4 + r][wid * 16 + l15]      = s0[r];
            Ss[16 + quad * 4 + r][wid * 16 + l15] = s1[r];
        }
        __builtin_amdgcn_sched_barrier(0);
        // vf(i): consumed in PV(i) -- window spans b2 + softmax + b3
        bf16x8 vf[4][2];
        #pragma unroll
        for (int nt = 0; nt < 4; ++nt) {
            int dd = wid * 64 + nt * 16 + l15;
            const bf16* vrow = Vb + (size_t)dd * (BB * LL) + j0;
            vf[nt][0] = *(const bf16x8*)(vrow + quad * 8);
            vf[nt][1] = *(const bf16x8*)(vrow + 32 + quad * 8);
        }
        // srel(i+1): consumed in softmax(i+1) -- window > full iteration
        bf16x8 srelNext = *(const bf16x8*)(Sb + (size_t)srow * LL + jc + ssg * 8);
        __builtin_amdgcn_sched_barrier(0);

        asm volatile("s_waitcnt lgkmcnt(0)\ns_barrier" ::: "memory");   // b2: Ss handoff

        // ===== softmax =====
        // kf(i+1) first: window = softmax + b3 + PV + loopback
        #pragma unroll
        for (int ks = 0; ks < 8; ++ks)
            kf[ks] = *(const bf16x8*)(Kb + (size_t)(jc + jrow) * DKK + ks * 32 + quad * 8);
        __builtin_amdgcn_sched_barrier(0);
        {
            int r = tid >> 3, sg = tid & 7;
            int i = i0 + r;
            float v[8];
            #pragma unroll
            for (int c = 0; c < 8; ++c) {
                float sr = (j0 + sg * 8 + c == i + 1) ? 0.f : (float)srelCur[c];
                v[c] = (Ss[r][sg * 8 + c] + sr) * 0.0625f;
            }
            float tmax = v[0];
            #pragma unroll
            for (int c = 1; c < 8; ++c) tmax = fmaxf(tmax, v[c]);
            tmax = fmaxf(tmax, __shfl_xor(tmax, 1));
            tmax = fmaxf(tmax, __shfl_xor(tmax, 2));
            tmax = fmaxf(tmax, __shfl_xor(tmax, 4));
            float mOld = mSt[r], lOld = lSt[r];
            float mNew = fmaxf(mOld, tmax);
            float alpha = __expf(mOld - mNew);
            float ps = 0.f;
            bf16x8 pv;
            #pragma unroll
            for (int c = 0; c < 8; ++c) {
                float p = __expf(v[c] - mNew);
                ps += p;
                pv[c] = (bf16)p;
            }
            ps += __shfl_xor(ps, 1);
            ps += __shfl_xor(ps, 2);
            ps += __shfl_xor(ps, 4);
            *(bf16x8*)&Ps[r][sg * 8] = pv;
            if (sg == 0) { mSt[r] = mNew; lSt[r] = alpha * lOld + ps; aSt[r] = alpha; }
        }
        srelCur = srelNext;
        asm volatile("s_waitcnt lgkmcnt(0)\ns_barrier" ::: "memory");   // b3: Ps handoff

        // ===== PV phase (vf lands here; compiler-placed vmcnt wait) =====
        bf16x8 aF[2][2];
        #pragma unroll
        for (int rt = 0; rt < 2; ++rt)
            #pragma unroll
            for (int kk = 0; kk < 2; ++kk)
                aF[rt][kk] = *(const bf16x8*)&Ps[rt * 16 + l15][kk * 32 + quad * 8];
        float ar[2][4];
        #pragma unroll
        for (int rt = 0; rt < 2; ++rt)
            #pragma unroll
            for (int r = 0; r < 4; ++r) ar[rt][r] = aSt[rt * 16 + quad * 4 + r];
        __builtin_amdgcn_s_setprio(1);
        #pragma unroll
        for (int nt = 0; nt < 4; ++nt) {
            #pragma unroll
            for (int rt = 0; rt < 2; ++rt) {
                f32x4 o = accO[rt][nt];
                o[0] *= ar[rt][0]; o[1] *= ar[rt][1];
                o[2] *= ar[rt][2]; o[3] *= ar[rt][3];
                o = __builtin_amdgcn_mfma_f32_16x16x32_bf16(aF[rt][0], vf[nt][0], o, 0, 0, 0);
                o = __builtin_amdgcn_mfma_f32_16x16x32_bf16(aF[rt][1], vf[nt][1], o, 0, 0, 0);
                accO[rt][nt] = o;
            }
        }
        __builtin_amdgcn_s_setprio(0);
        // no trailing barrier: Ss WAR covered by b3(i), Ps/aSt WAR by b2(i+1)
    }
    float lr[2][4];
    #pragma unroll
    for (int rt = 0; rt < 2; ++rt)
        #pragma unroll
        for (int r = 0; r < 4; ++r) lr[rt][r] = 1.f / lSt[rt * 16 + quad * 4 + r];
    #pragma unroll
    for (int rt = 0; rt < 2; ++rt)
        #pragma unroll
        for (int nt = 0; nt < 4; ++nt)
            #pragma unroll
            for (int r = 0; r < 4; ++r) {
                int i = i0 + rt * 16 + quad * 4 + r;
                int d = dh * 256 + wid * 64 + nt * 16 + l15;
                out[((size_t)b * LL + i) * DD + d] = accO[rt][nt][r] * lr[rt][r];
            }
}

extern "C" void kernel_launch(void* const* d_in, const int* in_sizes, int n_in,
                              void* d_out, int out_size, void* d_ws, size_t ws_size,
                              hipStream_t stream) {
    const float* inQ = (const float*)d_in[0];
    const float* inK = (const float*)d_in[1];
    const float* inV = (const float*)d_in[2];
    const float* Wq  = (const float*)d_in[3];
    const float* Wk  = (const float*)d_in[4];
    const float* Wv  = (const float*)d_in[5];
    const float* E   = (const float*)d_in[6];
    float* out = (float*)d_out;

    char* ws = (char*)d_ws;
    bf16* Qw   = (bf16*)(ws);                         // 4 MB  [B*L][DK]
    bf16* Kw   = (bf16*)(ws + ((size_t)4  << 20));    // 4 MB  [B*L][DK]
    bf16* Vt   = (bf16*)(ws + ((size_t)8  << 20));    // 8 MB  [D][B*L]
    bf16* SrelW= (bf16*)(ws + ((size_t)16 << 20));    // 32 MB [B,L,L] skewed
    // transient buffers inside the Srel region (dead before QE writes Srel):
    bf16* Xq   = (bf16*)(ws + ((size_t)16 << 20));    // 8 MB  inQ as bf16
    bf16* Xk   = (bf16*)(ws + ((size_t)24 << 20));    // 8 MB
    bf16* Xv   = (bf16*)(ws + ((size_t)32 << 20));    // 8 MB
    bf16* Vw   = (bf16*)(ws + ((size_t)40 << 20));    // 8 MB  V row-major
    bf16* WqT  = (bf16*)(ws + ((size_t)48 << 20));            // [DK][D]
    bf16* WkT  = (bf16*)(ws + ((size_t)48 << 20) + 262144);   // [DK][D]
    bf16* WvT  = (bf16*)(ws + ((size_t)48 << 20) + 524288);   // [D][D]
    bf16* Eb   = (bf16*)(ws + ((size_t)49 << 20));            // [L][DK]

    conv3_f32_bf16<<<dim3(4096, 3), 256, 0, stream>>>(inQ, inK, inV, Xq, Xk, Xv,
                                                      (BB * LL * DD) / 4);
    conv_f32_bf16v<<<512,  256, 0, stream>>>(E, Eb, (LL * DKK) / 4);
    transpose_f32_bf16<<<512,  256, 0, stream>>>(Wq, WqT, DD, DKK);
    transpose_f32_bf16<<<512,  256, 0, stream>>>(Wk, WkT, DD, DKK);
    transpose_f32_bf16<<<1024, 256, 0, stream>>>(Wv, WvT, DD, DD);

    // Q = Xq·Wq^T' and K = Xk·Wk^T' fused via blockIdx.y: M=8192 N=256 K=512
    gemm128<0><<<dim3(2 * 64, 2),  256, 0, stream>>>(Xq, WqT, Qw, DKK, DD,
                                                     4194304L, 131072L, 2097152L);
    // Vw = Xv·Wv^T': M=8192 N=512 K=512
    gemm128<0><<<dim3(4 * 64, 1),  256, 0, stream>>>(Xv, WvT, Vw, DD, DD, 0, 0, 0);
    // Vt = Vw^T  [512][8192]
    transpose_bf16_tile<<<(DD / 64) * (BB * LL / 64), 256, 0, stream>>>(Vw, Vt, BB * LL, DD);
    // Srel (skewed) = skew(Q·E^T): per-batch M=N=2048 K=256
    gemm128<1><<<dim3(16 * 16, BB), 256, 0, stream>>>(Qw, Eb, SrelW, LL, DKK,
                                                      (long)LL * DKK, 0, (long)LL * LL);
    attn_kernel<<<dim3(BB * 64 * 2), 256, 0, stream>>>(Qw, Kw, Vt, SrelW, out);
}

// Round 6
// 235.139 us; speedup vs baseline: 1.2312x; 1.2312x over previous
//
#include <hip/hip_runtime.h>
#include <hip/hip_bf16.h>

#define BB 4
#define LL 2048
#define DD 512
#define DKK 256

typedef __bf16 bf16;
typedef __bf16 bf16x4 __attribute__((ext_vector_type(4)));
typedef __bf16 bf16x8 __attribute__((ext_vector_type(8)));
typedef float f32x4 __attribute__((ext_vector_type(4)));

__device__ __forceinline__ void async_ld16(const bf16* g, bf16* l) {
    __builtin_amdgcn_global_load_lds(
        (const __attribute__((address_space(1))) void*)g,
        (__attribute__((address_space(3))) void*)l, 16, 0, 0);
}

// fused bf16 conversion of the three [B,L,D] activations (one launch)
__global__ void conv3_f32_bf16(const float* __restrict__ a, const float* __restrict__ bq,
                               const float* __restrict__ c,
                               bf16* __restrict__ oa, bf16* __restrict__ ob,
                               bf16* __restrict__ oc, int n4) {
    const float* in = (blockIdx.y == 0) ? a : (blockIdx.y == 1) ? bq : c;
    bf16* out = (blockIdx.y == 0) ? oa : (blockIdx.y == 1) ? ob : oc;
    int i = blockIdx.x * 256 + threadIdx.x;
    if (i < n4) {
        f32x4 v = *(const f32x4*)(in + (size_t)i * 4);
        bf16x4 o;
        #pragma unroll
        for (int j = 0; j < 4; ++j) o[j] = (bf16)v[j];
        *(bf16x4*)(out + (size_t)i * 4) = o;
    }
}

__global__ void conv_f32_bf16v(const float* __restrict__ in, bf16* __restrict__ out, int n4) {
    int i = blockIdx.x * 256 + threadIdx.x;
    if (i < n4) {
        f32x4 v = *(const f32x4*)(in + (size_t)i * 4);
        bf16x4 o;
        #pragma unroll
        for (int j = 0; j < 4; ++j) o[j] = (bf16)v[j];
        *(bf16x4*)(out + (size_t)i * 4) = o;
    }
}

__global__ void transpose_f32_bf16(const float* __restrict__ in, bf16* __restrict__ out,
                                   int R, int C) {
    int idx = blockIdx.x * 256 + threadIdx.x;
    if (idx < R * C) {
        int r = idx / C, c = idx % C;
        out[(size_t)c * R + r] = (bf16)in[idx];
    }
}

// Unified bf16 GEMM, m97-style: C[m][n] = sum_k A[m][k]*B[n][k].  128x128 tile,
// 4 waves (each 64x64 = 4x4 acc).  A and B staged direct-to-LDS via
// global_load_lds(16B) with parity-rotation swizzle.  Staging global addresses
// are persistent pointers bumped by a constant per K-step (no per-iter 64-bit
// addr recompute).  bStride lets blockIdx.y batch over different B operands.
// SKEW=1: scatter-store into skewed Srel layout.
// TRANSV=1: write C^T directly (Vt[n][m], row stride BB*LL) via an LDS bounce
//           -- replaces the separate Vw->Vt transpose kernel.  tbuf row stride
//           136 (NOT 134: stride must be ≡0 mod 8 elements so the bf16x8 reads
//           stay 16B-aligned; 134 gave misaligned ds_read_b128 -> memviol).
template <int SKEW, int TRANSV>
__launch_bounds__(256, 2)
__global__ void gemm128(const bf16* __restrict__ A, const bf16* __restrict__ B,
                        bf16* __restrict__ C, int N, int K,
                        long aStride, long bStride, long cStride)
{
    __shared__ bf16 Als[128 * 32];
    __shared__ bf16 Bls[128 * 32];
    __shared__ bf16 tbuf[TRANSV ? 64 * 136 : 1];

    int tid  = threadIdx.x;
    int lane = tid & 63;
    int wid  = tid >> 6;
    int l15  = lane & 15;
    int quad = lane >> 4;
    int nb = N >> 7;
    int gx = blockIdx.x % nb;
    int gy = blockIdx.x / nb;

    const bf16* Ab = A + (size_t)blockIdx.y * aStride + (size_t)gy * 128 * K;
    const bf16* Bb = B + (size_t)blockIdx.y * bStride + (size_t)gx * 128 * K;

    int rl = lane >> 2;     // staging: row within 16-row inst
    int sl = lane & 3;      // staging: slot
    int half = wid & 1;     // waves 0/2: rows 0-63; waves 1/3: rows 64-127
    const bf16* gsrc = (wid < 2) ? Ab : Bb;
    bf16* ldst = (wid < 2) ? Als : Bls;

    // persistent staging pointers, bumped by +32 elements per K-step
    const bf16* gptr[4];
    #pragma unroll
    for (int u = 0; u < 4; ++u) {
        int inst = half * 4 + u;
        int row  = inst * 16 + rl;
        int c    = (sl - (row >> 1)) & 3;
        gptr[u] = gsrc + (size_t)row * K + c * 8;
    }

    f32x4 acc[4][4];
    #pragma unroll
    for (int i = 0; i < 4; ++i)
        #pragma unroll
        for (int j = 0; j < 4; ++j) acc[i][j] = 0;

    for (int k0 = 0; k0 < K; k0 += 32) {
        #pragma unroll
        for (int u = 0; u < 4; ++u) {
            async_ld16(gptr[u], ldst + (half * 4 + u) * 512);
            gptr[u] += 32;
        }
        __syncthreads();   // drains vmcnt(0): staging complete
        bf16x8 fA[4], fB[4];
        #pragma unroll
        for (int rt = 0; rt < 4; ++rt) {
            int row = (wid & 1) * 64 + rt * 16 + l15;
            int s   = (quad + (row >> 1)) & 3;
            fA[rt] = *(const bf16x8*)&Als[row * 32 + s * 8];
        }
        #pragma unroll
        for (int ct = 0; ct < 4; ++ct) {
            int col = (wid >> 1) * 64 + ct * 16 + l15;
            int s   = (quad + (col >> 1)) & 3;
            fB[ct] = *(const bf16x8*)&Bls[col * 32 + s * 8];
        }
        #pragma unroll
        for (int rt = 0; rt < 4; ++rt)
            #pragma unroll
            for (int ct = 0; ct < 4; ++ct)
                acc[rt][ct] = __builtin_amdgcn_mfma_f32_16x16x32_bf16(
                                  fA[rt], fB[ct], acc[rt][ct], 0, 0, 0);
        __syncthreads();   // LDS reuse guard
    }

    bf16* Cb = C + (size_t)blockIdx.y * cStride;
    int m0 = gy * 128 + (wid & 1) * 64;
    int n0 = gx * 128 + (wid >> 1) * 64;
    if (TRANSV) {
        // C^T -> Vt[n][m], n = gx*128+[0,128), m = gy*128+[0,128).
        // Two rounds of 64 n-rows through tbuf [64][136].
        #pragma unroll
        for (int p = 0; p < 2; ++p) {
            if ((wid >> 1) == p) {
                #pragma unroll
                for (int rt = 0; rt < 4; ++rt)
                    #pragma unroll
                    for (int ct = 0; ct < 4; ++ct)
                        #pragma unroll
                        for (int r = 0; r < 4; ++r)
                            tbuf[(ct * 16 + l15) * 136
                                 + (wid & 1) * 64 + rt * 16 + quad * 4 + r]
                                = (bf16)acc[rt][ct][r];
            }
            __syncthreads();
            int row = tid >> 2, c0 = (tid & 3) * 32;
            bf16* dst = C + (size_t)(gx * 128 + p * 64 + row) * (BB * LL)
                          + (size_t)gy * 128 + c0;
            #pragma unroll
            for (int q = 0; q < 4; ++q)
                *(bf16x8*)(dst + q * 8) = *(const bf16x8*)&tbuf[row * 136 + c0 + q * 8];
            __syncthreads();
        }
    } else if (!SKEW) {
        #pragma unroll
        for (int rt = 0; rt < 4; ++rt)
            #pragma unroll
            for (int ct = 0; ct < 4; ++ct)
                #pragma unroll
                for (int r = 0; r < 4; ++r) {
                    int m = m0 + rt * 16 + quad * 4 + r;
                    int n = n0 + ct * 16 + l15;
                    Cb[(size_t)m * N + n] = (bf16)acc[rt][ct][r];
                }
    } else {
        #pragma unroll
        for (int rt = 0; rt < 4; ++rt)
            #pragma unroll
            for (int ct = 0; ct < 4; ++ct)
                #pragma unroll
                for (int r = 0; r < 4; ++r) {
                    int row = m0 + rt * 16 + quad * 4 + r;
                    int c   = n0 + ct * 16 + l15;
                    bool lower = (c >= LL - 1 - row);
                    int dr = lower ? row : row - 1;
                    int dc = lower ? c - (LL - 1 - row) : c + row + 1;
                    if (lower || row >= 1)
                        Cb[(size_t)dr * LL + dc] = (bf16)acc[rt][ct][r];
                }
    }
}

// Fused attention, R13 = R9 structure (proven 85us) + pointer-increment
// staging.  One-ahead SPLIT staging with counted vmcnt: K(i+1) issued after
// QK(i)'s kf reads; V(i+1) after PV(i)'s vf reads; srel(i+1) prefetched in
// QK(i).  Staging is WAVE-LOCAL (wave w stages exactly the K rows [16w,16w+16)
// / V rows [64w,64w+64) it reads), so only lgkm(0) of the wave's own LDS reads
// is needed before re-staging -- no barrier.  Two raw s_barriers/iter (Ss
// handoff b2, Ps handoff b3) with lgkm-only drains: in-flight global_load_lds
// survive the barriers.  Waits: vmcnt(9) before kf reads (drains K(i);
// srel+V(i)=9 stay), vmcnt(9) before vf reads (drains V(i); K(i+1)+srel=9
// stay; vmcnt(0) last iter).  The 16 staging source addresses and the srel
// address are persistent VGPR pointers bumped by constants per iter
// (K: +64*DKK, V: +64, srel: +64) -- removes ~100 VALU/wave/iter of 64-bit
// address recompute (the R9 VALUBusy=26% hotspot).  Issue counts/order are
// byte-identical to R9, so the vmcnt choreography is unchanged.
__launch_bounds__(256, 2)
__global__ void attn_kernel(const bf16* __restrict__ Qw, const bf16* __restrict__ Kw,
                            const bf16* __restrict__ Vt, const bf16* __restrict__ Srel,
                            float* __restrict__ out)
{
    __shared__ bf16  Klds[64 * 256];      // rows j (64), 32 chunks of 8, rotated
    __shared__ bf16  Vlds[256 * 64];      // rows d (256), 8 chunks of 8, rotated
    __shared__ float Ss[32][68];
    __shared__ bf16  Ps[32][72];
    __shared__ float mSt[32], lSt[32], aSt[32];

    int tid  = threadIdx.x;
    int lane = tid & 63;
    int wid  = tid >> 6;
    int l15  = lane & 15;
    int quad = lane >> 4;

    int xcd = blockIdx.x & 7;          // XCD = blockIdx % 8 (round-robin dispatch)
    int b   = xcd >> 1;
    int dh  = xcd & 1;
    int i0  = (blockIdx.x >> 3) * 32;

    const bf16* Qb = Qw + (size_t)b * LL * DKK;
    const bf16* Kb = Kw + (size_t)b * LL * DKK;
    const bf16* Sb = Srel + (size_t)b * LL * LL;
    const bf16* Vb = Vt + (size_t)(dh * 256) * (BB * LL) + (size_t)b * LL;

    // persistent staging pointers (wave-local rows), bumped per iteration
    const bf16* kptr[8];
    const bf16* vptr[8];
    #pragma unroll
    for (int u = 0; u < 8; ++u) {
        int inst = wid * 8 + u;
        int j_ = inst * 2 + (lane >> 5);
        int ck = ((lane & 31) - j_) & 31;
        kptr[u] = Kb + (size_t)j_ * DKK + ck * 8;
        int d_ = inst * 8 + (lane >> 3);
        int cv = ((lane & 7) - d_) & 7;
        vptr[u] = Vb + (size_t)d_ * (BB * LL) + cv * 8;
    }

    bf16x8 Qreg[2][8];
    #pragma unroll
    for (int rt = 0; rt < 2; ++rt)
        #pragma unroll
        for (int ks = 0; ks < 8; ++ks)
            Qreg[rt][ks] = *(const bf16x8*)(Qb + (size_t)(i0 + rt * 16 + l15) * DKK
                                            + ks * 32 + quad * 8);

    if (tid < 32) { mSt[tid] = -1e30f; lSt[tid] = 0.f; }

    f32x4 accO[2][4];
    #pragma unroll
    for (int rt = 0; rt < 2; ++rt)
        #pragma unroll
        for (int nt = 0; nt < 4; ++nt) accO[rt][nt] = 0;

    // drain Qreg loads before the counted staging stream starts
    asm volatile("s_waitcnt vmcnt(0)" ::: "memory");

    // ---- prologue (issue order defines vmcnt counts): K0(8), srel0(1), V0(8)
    #pragma unroll
    for (int u = 0; u < 8; ++u) {
        async_ld16(kptr[u], Klds + (wid * 8 + u) * 512);
        kptr[u] += 64 * DKK;
    }
    __builtin_amdgcn_sched_barrier(0);
    int srow = i0 + (tid >> 3), ssg = tid & 7;
    bf16x8 srelCur = *(const bf16x8*)(Sb + (size_t)srow * LL + ssg * 8);
    const bf16* sPtr = Sb + (size_t)srow * LL + ssg * 8 + 64;
    __builtin_amdgcn_sched_barrier(0);
    #pragma unroll
    for (int u = 0; u < 8; ++u) {
        async_ld16(vptr[u], Vlds + (wid * 8 + u) * 512);
        vptr[u] += 64;
    }

    int jrow = wid * 16 + l15;

    for (int j0 = 0; j0 < LL; j0 += 64) {
        bool notlast = (j0 + 64 < LL);

        // ===== QK phase =====
        asm volatile("s_waitcnt vmcnt(9)" ::: "memory");   // K(i) staged
        bf16x8 kf[8];
        #pragma unroll
        for (int ks = 0; ks < 8; ++ks) {
            int cp = (ks * 4 + quad + jrow) & 31;
            kf[ks] = *(const bf16x8*)&Klds[jrow * 256 + cp * 8];
        }
        asm volatile("s_waitcnt lgkmcnt(0)" ::: "memory"); // own kf reads done
        __builtin_amdgcn_sched_barrier(0);
        if (notlast) {                                     // K(i+1) in flight
            #pragma unroll
            for (int u = 0; u < 8; ++u) {
                async_ld16(kptr[u], Klds + (wid * 8 + u) * 512);
                kptr[u] += 64 * DKK;
            }
        }
        __builtin_amdgcn_sched_barrier(0);
        bf16x8 srelNext;
        if (notlast) {                                     // srel(i+1) in flight
            srelNext = *(const bf16x8*)sPtr;
            sPtr += 64;
        }
        __builtin_amdgcn_sched_barrier(0);
        f32x4 s0 = 0, s1 = 0;
        __builtin_amdgcn_s_setprio(1);
        #pragma unroll
        for (int ks = 0; ks < 8; ++ks) {
            s0 = __builtin_amdgcn_mfma_f32_16x16x32_bf16(Qreg[0][ks], kf[ks], s0, 0, 0, 0);
            s1 = __builtin_amdgcn_mfma_f32_16x16x32_bf16(Qreg[1][ks], kf[ks], s1, 0, 0, 0);
        }
        __builtin_amdgcn_s_setprio(0);
        #pragma unroll
        for (int r = 0; r < 4; ++r) {
            Ss[quad * 4 + r][wid * 16 + l15]      = s0[r];
            Ss[16 + quad * 4 + r][wid * 16 + l15] = s1[r];
        }
        asm volatile("s_waitcnt lgkmcnt(0)\ns_barrier" ::: "memory");   // b2: Ss handoff

        // ===== softmax =====
        {
            int r = tid >> 3, sg = tid & 7;
            int i = i0 + r;
            float v[8];
            #pragma unroll
            for (int c = 0; c < 8; ++c) {
                float sr = (j0 + sg * 8 + c == i + 1) ? 0.f : (float)srelCur[c];
                v[c] = (Ss[r][sg * 8 + c] + sr) * 0.0625f;
            }
            float tmax = v[0];
            #pragma unroll
            for (int c = 1; c < 8; ++c) tmax = fmaxf(tmax, v[c]);
            tmax = fmaxf(tmax, __shfl_xor(tmax, 1));
            tmax = fmaxf(tmax, __shfl_xor(tmax, 2));
            tmax = fmaxf(tmax, __shfl_xor(tmax, 4));
            float mOld = mSt[r], lOld = lSt[r];
            float mNew = fmaxf(mOld, tmax);
            float alpha = __expf(mOld - mNew);
            float ps = 0.f;
            bf16x8 pv;
            #pragma unroll
            for (int c = 0; c < 8; ++c) {
                float p = __expf(v[c] - mNew);
                ps += p;
                pv[c] = (bf16)p;
            }
            ps += __shfl_xor(ps, 1);
            ps += __shfl_xor(ps, 2);
            ps += __shfl_xor(ps, 4);
            *(bf16x8*)&Ps[r][sg * 8] = pv;
            if (sg == 0) { mSt[r] = mNew; lSt[r] = alpha * lOld + ps; aSt[r] = alpha; }
        }
        srelCur = srelNext;
        asm volatile("s_waitcnt lgkmcnt(0)\ns_barrier" ::: "memory");   // b3: Ps handoff

        // ===== PV phase =====
        if (notlast) asm volatile("s_waitcnt vmcnt(9)" ::: "memory");   // V(i) staged
        else         asm volatile("s_waitcnt vmcnt(0)" ::: "memory");
        bf16x8 aF[2][2];
        #pragma unroll
        for (int rt = 0; rt < 2; ++rt)
            #pragma unroll
            for (int kk = 0; kk < 2; ++kk)
                aF[rt][kk] = *(const bf16x8*)&Ps[rt * 16 + l15][kk * 32 + quad * 8];
        float ar[2][4];
        #pragma unroll
        for (int rt = 0; rt < 2; ++rt)
            #pragma unroll
            for (int r = 0; r < 4; ++r) ar[rt][r] = aSt[rt * 16 + quad * 4 + r];
        bf16x8 vf[4][2];
        #pragma unroll
        for (int nt = 0; nt < 4; ++nt) {
            int dd = wid * 64 + nt * 16 + l15;
            int c0 = (quad + dd) & 7;
            int c1 = (4 + quad + dd) & 7;
            vf[nt][0] = *(const bf16x8*)&Vlds[dd * 64 + c0 * 8];
            vf[nt][1] = *(const bf16x8*)&Vlds[dd * 64 + c1 * 8];
        }
        asm volatile("s_waitcnt lgkmcnt(0)" ::: "memory"); // own Ps/vf reads done
        __builtin_amdgcn_sched_barrier(0);
        if (notlast) {                                     // V(i+1) in flight
            #pragma unroll
            for (int u = 0; u < 8; ++u) {
                async_ld16(vptr[u], Vlds + (wid * 8 + u) * 512);
                vptr[u] += 64;
            }
        }
        __builtin_amdgcn_sched_barrier(0);
        __builtin_amdgcn_s_setprio(1);
        #pragma unroll
        for (int nt = 0; nt < 4; ++nt) {
            #pragma unroll
            for (int rt = 0; rt < 2; ++rt) {
                f32x4 o = accO[rt][nt];
                o[0] *= ar[rt][0]; o[1] *= ar[rt][1];
                o[2] *= ar[rt][2]; o[3] *= ar[rt][3];
                o = __builtin_amdgcn_mfma_f32_16x16x32_bf16(aF[rt][0], vf[nt][0], o, 0, 0, 0);
                o = __builtin_amdgcn_mfma_f32_16x16x32_bf16(aF[rt][1], vf[nt][1], o, 0, 0, 0);
                accO[rt][nt] = o;
            }
        }
        __builtin_amdgcn_s_setprio(0);
        // no trailing barrier: Ss WAR covered by b3(i), Ps/aSt WAR by b2(i+1)
    }
    float lr[2][4];
    #pragma unroll
    for (int rt = 0; rt < 2; ++rt)
        #pragma unroll
        for (int r = 0; r < 4; ++r) lr[rt][r] = 1.f / lSt[rt * 16 + quad * 4 + r];
    #pragma unroll
    for (int rt = 0; rt < 2; ++rt)
        #pragma unroll
        for (int nt = 0; nt < 4; ++nt)
            #pragma unroll
            for (int r = 0; r < 4; ++r) {
                int i = i0 + rt * 16 + quad * 4 + r;
                int d = dh * 256 + wid * 64 + nt * 16 + l15;
                out[((size_t)b * LL + i) * DD + d] = accO[rt][nt][r] * lr[rt][r];
            }
}

extern "C" void kernel_launch(void* const* d_in, const int* in_sizes, int n_in,
                              void* d_out, int out_size, void* d_ws, size_t ws_size,
                              hipStream_t stream) {
    const float* inQ = (const float*)d_in[0];
    const float* inK = (const float*)d_in[1];
    const float* inV = (const float*)d_in[2];
    const float* Wq  = (const float*)d_in[3];
    const float* Wk  = (const float*)d_in[4];
    const float* Wv  = (const float*)d_in[5];
    const float* E   = (const float*)d_in[6];
    float* out = (float*)d_out;

    char* ws = (char*)d_ws;
    bf16* Qw   = (bf16*)(ws);                         // 4 MB  [B*L][DK]
    bf16* Kw   = (bf16*)(ws + ((size_t)4  << 20));    // 4 MB  [B*L][DK]
    bf16* Vt   = (bf16*)(ws + ((size_t)8  << 20));    // 8 MB  [D][B*L]
    bf16* SrelW= (bf16*)(ws + ((size_t)16 << 20));    // 32 MB [B,L,L] skewed
    // transient buffers inside the Srel region (dead before QE writes Srel):
    bf16* Xq   = (bf16*)(ws + ((size_t)16 << 20));    // 8 MB  inQ as bf16
    bf16* Xk   = (bf16*)(ws + ((size_t)24 << 20));    // 8 MB
    bf16* Xv   = (bf16*)(ws + ((size_t)32 << 20));    // 8 MB
    bf16* WqT  = (bf16*)(ws + ((size_t)48 << 20));            // [DK][D]
    bf16* WkT  = (bf16*)(ws + ((size_t)48 << 20) + 262144);   // [DK][D]
    bf16* WvT  = (bf16*)(ws + ((size_t)48 << 20) + 524288);   // [D][D]
    bf16* Eb   = (bf16*)(ws + ((size_t)49 << 20));            // [L][DK]

    conv3_f32_bf16<<<dim3(4096, 3), 256, 0, stream>>>(inQ, inK, inV, Xq, Xk, Xv,
                                                      (BB * LL * DD) / 4);
    conv_f32_bf16v<<<512,  256, 0, stream>>>(E, Eb, (LL * DKK) / 4);
    transpose_f32_bf16<<<512,  256, 0, stream>>>(Wq, WqT, DD, DKK);
    transpose_f32_bf16<<<512,  256, 0, stream>>>(Wk, WkT, DD, DKK);
    transpose_f32_bf16<<<1024, 256, 0, stream>>>(Wv, WvT, DD, DD);

    // Q = Xq·Wq^T' and K = Xk·Wk^T' fused via blockIdx.y: M=8192 N=256 K=512
    gemm128<0, 0><<<dim3(2 * 64, 2),  256, 0, stream>>>(Xq, WqT, Qw, DKK, DD,
                                                        4194304L, 131072L, 2097152L);
    // Vt = (Xv·Wv^T')^T written directly (fused transpose): M=8192 N=512 K=512
    gemm128<0, 1><<<dim3(4 * 64, 1),  256, 0, stream>>>(Xv, WvT, Vt, DD, DD, 0, 0, 0);
    // Srel (skewed) = skew(Q·E^T): per-batch M=N=2048 K=256
    gemm128<1, 0><<<dim3(16 * 16, BB), 256, 0, stream>>>(Qw, Eb, SrelW, LL, DKK,
                                                         (long)LL * DKK, 0, (long)LL * LL);
    attn_kernel<<<dim3(BB * 64 * 2), 256, 0, stream>>>(Qw, Kw, Vt, SrelW, out);
}

// Round 7
// 234.676 us; speedup vs baseline: 1.2336x; 1.0020x over previous
//
#include <hip/hip_runtime.h>
#include <hip/hip_bf16.h>

#define BB 4
#define LL 2048
#define DD 512
#define DKK 256

typedef __bf16 bf16;
typedef __bf16 bf16x4 __attribute__((ext_vector_type(4)));
typedef __bf16 bf16x8 __attribute__((ext_vector_type(8)));
typedef float f32x4 __attribute__((ext_vector_type(4)));

__device__ __forceinline__ void async_ld16(const bf16* g, bf16* l) {
    __builtin_amdgcn_global_load_lds(
        (const __attribute__((address_space(1))) void*)g,
        (__attribute__((address_space(3))) void*)l, 16, 0, 0);
}

// fused bf16 conversion of the three [B,L,D] activations (one launch)
__global__ void conv3_f32_bf16(const float* __restrict__ a, const float* __restrict__ bq,
                               const float* __restrict__ c,
                               bf16* __restrict__ oa, bf16* __restrict__ ob,
                               bf16* __restrict__ oc, int n4) {
    const float* in = (blockIdx.y == 0) ? a : (blockIdx.y == 1) ? bq : c;
    bf16* out = (blockIdx.y == 0) ? oa : (blockIdx.y == 1) ? ob : oc;
    int i = blockIdx.x * 256 + threadIdx.x;
    if (i < n4) {
        f32x4 v = *(const f32x4*)(in + (size_t)i * 4);
        bf16x4 o;
        #pragma unroll
        for (int j = 0; j < 4; ++j) o[j] = (bf16)v[j];
        *(bf16x4*)(out + (size_t)i * 4) = o;
    }
}

// merged prep: E conversion + Wq/Wk/Wv transposes in one launch (blockIdx.y)
__global__ void prep_misc(const float* __restrict__ E, const float* __restrict__ Wq,
                          const float* __restrict__ Wk, const float* __restrict__ Wv,
                          bf16* __restrict__ Eb, bf16* __restrict__ WqT,
                          bf16* __restrict__ WkT, bf16* __restrict__ WvT) {
    int y = blockIdx.y;
    int idx = blockIdx.x * 256 + threadIdx.x;
    if (y == 0) {
        if (idx < (LL * DKK) / 4) {
            f32x4 v = *(const f32x4*)(E + (size_t)idx * 4);
            bf16x4 o;
            #pragma unroll
            for (int j = 0; j < 4; ++j) o[j] = (bf16)v[j];
            *(bf16x4*)(Eb + (size_t)idx * 4) = o;
        }
    } else if (y == 1) {
        if (idx < DD * DKK) { int r = idx / DKK, c = idx % DKK; WqT[(size_t)c * DD + r] = (bf16)Wq[idx]; }
    } else if (y == 2) {
        if (idx < DD * DKK) { int r = idx / DKK, c = idx % DKK; WkT[(size_t)c * DD + r] = (bf16)Wk[idx]; }
    } else {
        if (idx < DD * DD)  { int r = idx / DD,  c = idx % DD;  WvT[(size_t)c * DD + r] = (bf16)Wv[idx]; }
    }
}

// Unified bf16 GEMM, m97-style (R13-proven).  SKEW=1: skewed Srel scatter.
// TRANSV=1: write C^T via LDS bounce (tbuf stride 136: 16B-aligned b128 rows).
template <int SKEW, int TRANSV>
__launch_bounds__(256, 2)
__global__ void gemm128(const bf16* __restrict__ A, const bf16* __restrict__ B,
                        bf16* __restrict__ C, int N, int K,
                        long aStride, long bStride, long cStride)
{
    __shared__ bf16 Als[128 * 32];
    __shared__ bf16 Bls[128 * 32];
    __shared__ bf16 tbuf[TRANSV ? 64 * 136 : 1];

    int tid  = threadIdx.x;
    int lane = tid & 63;
    int wid  = tid >> 6;
    int l15  = lane & 15;
    int quad = lane >> 4;
    int nb = N >> 7;
    int gx = blockIdx.x % nb;
    int gy = blockIdx.x / nb;

    const bf16* Ab = A + (size_t)blockIdx.y * aStride + (size_t)gy * 128 * K;
    const bf16* Bb = B + (size_t)blockIdx.y * bStride + (size_t)gx * 128 * K;

    int rl = lane >> 2;
    int sl = lane & 3;
    int half = wid & 1;
    const bf16* gsrc = (wid < 2) ? Ab : Bb;
    bf16* ldst = (wid < 2) ? Als : Bls;

    const bf16* gptr[4];
    #pragma unroll
    for (int u = 0; u < 4; ++u) {
        int inst = half * 4 + u;
        int row  = inst * 16 + rl;
        int c    = (sl - (row >> 1)) & 3;
        gptr[u] = gsrc + (size_t)row * K + c * 8;
    }

    f32x4 acc[4][4];
    #pragma unroll
    for (int i = 0; i < 4; ++i)
        #pragma unroll
        for (int j = 0; j < 4; ++j) acc[i][j] = 0;

    for (int k0 = 0; k0 < K; k0 += 32) {
        #pragma unroll
        for (int u = 0; u < 4; ++u) {
            async_ld16(gptr[u], ldst + (half * 4 + u) * 512);
            gptr[u] += 32;
        }
        __syncthreads();
        bf16x8 fA[4], fB[4];
        #pragma unroll
        for (int rt = 0; rt < 4; ++rt) {
            int row = (wid & 1) * 64 + rt * 16 + l15;
            int s   = (quad + (row >> 1)) & 3;
            fA[rt] = *(const bf16x8*)&Als[row * 32 + s * 8];
        }
        #pragma unroll
        for (int ct = 0; ct < 4; ++ct) {
            int col = (wid >> 1) * 64 + ct * 16 + l15;
            int s   = (quad + (col >> 1)) & 3;
            fB[ct] = *(const bf16x8*)&Bls[col * 32 + s * 8];
        }
        #pragma unroll
        for (int rt = 0; rt < 4; ++rt)
            #pragma unroll
            for (int ct = 0; ct < 4; ++ct)
                acc[rt][ct] = __builtin_amdgcn_mfma_f32_16x16x32_bf16(
                                  fA[rt], fB[ct], acc[rt][ct], 0, 0, 0);
        __syncthreads();
    }

    bf16* Cb = C + (size_t)blockIdx.y * cStride;
    int m0 = gy * 128 + (wid & 1) * 64;
    int n0 = gx * 128 + (wid >> 1) * 64;
    if (TRANSV) {
        #pragma unroll
        for (int p = 0; p < 2; ++p) {
            if ((wid >> 1) == p) {
                #pragma unroll
                for (int rt = 0; rt < 4; ++rt)
                    #pragma unroll
                    for (int ct = 0; ct < 4; ++ct)
                        #pragma unroll
                        for (int r = 0; r < 4; ++r)
                            tbuf[(ct * 16 + l15) * 136
                                 + (wid & 1) * 64 + rt * 16 + quad * 4 + r]
                                = (bf16)acc[rt][ct][r];
            }
            __syncthreads();
            int row = tid >> 2, c0 = (tid & 3) * 32;
            bf16* dst = C + (size_t)(gx * 128 + p * 64 + row) * (BB * LL)
                          + (size_t)gy * 128 + c0;
            #pragma unroll
            for (int q = 0; q < 4; ++q)
                *(bf16x8*)(dst + q * 8) = *(const bf16x8*)&tbuf[row * 136 + c0 + q * 8];
            __syncthreads();
        }
    } else if (!SKEW) {
        #pragma unroll
        for (int rt = 0; rt < 4; ++rt)
            #pragma unroll
            for (int ct = 0; ct < 4; ++ct)
                #pragma unroll
                for (int r = 0; r < 4; ++r) {
                    int m = m0 + rt * 16 + quad * 4 + r;
                    int n = n0 + ct * 16 + l15;
                    Cb[(size_t)m * N + n] = (bf16)acc[rt][ct][r];
                }
    } else {
        #pragma unroll
        for (int rt = 0; rt < 4; ++rt)
            #pragma unroll
            for (int ct = 0; ct < 4; ++ct)
                #pragma unroll
                for (int r = 0; r < 4; ++r) {
                    int row = m0 + rt * 16 + quad * 4 + r;
                    int c   = n0 + ct * 16 + l15;
                    bool lower = (c >= LL - 1 - row);
                    int dr = lower ? row : row - 1;
                    int dc = lower ? c - (LL - 1 - row) : c + row + 1;
                    if (lower || row >= 1)
                        Cb[(size_t)dr * LL + dc] = (bf16)acc[rt][ct][r];
                }
    }
}

// Fused attention R14: R13's proven staging (wave-local gload_lds, counted
// vmcnt, 2 raw lgkm-only barriers) + SWAPPED-QK IN-REGISTER SOFTMAX.
// mfma(kf, Qreg) gives lane S[q = rt*16+l15][j = wid*16+quad*4+r] -- the
// entire softmax (max, exp, sum) runs in registers with 2 quad-butterfly
// shuffles per reduction.  Cross-wave traffic shrinks to a 32x4 f32 partial-
// max tile at b2 (vs the old 8.7KB Ss f32 roundtrip + thread remap).  Running
// m and per-wave partial l live in REGISTERS (mSt/lSt deleted); l is merged
// across waves once at the end (valid since all waves share the same alpha
// sequence).  Srel is loaded coalesced (unchanged mapping) one iter ahead and
// bounced through a small double-buffered LDS tile SrelL[2][32][72] so the
// softmax can read it in MFMA layout off the critical path.  vmcnt: srel
// issued BEFORE K(i+1) so the compiler's precise wait at the SrelL write is
// vmcnt(8) (K staging stays in flight); manual waits: QK vmcnt(8) (K(i) done,
// V(i) in flight), PV vmcnt(8) (V(i) done, K(i+1) in flight; last iter 0).
// Hazard audit: pmax RAW=b2/WAR=b3; Ps,aSt RAW=b3/WAR=next b2; SrelL[p] RAW=
// b3(i-1)/WAR=two barriers; K/V staging wave-local as before.
__launch_bounds__(256, 2)
__global__ void attn_kernel(const bf16* __restrict__ Qw, const bf16* __restrict__ Kw,
                            const bf16* __restrict__ Vt, const bf16* __restrict__ Srel,
                            float* __restrict__ out)
{
    __shared__ bf16  Klds[64 * 256];
    __shared__ bf16  Vlds[256 * 64];
    __shared__ bf16  SrelL[2][32 * 72];   // [q][j], pad 72 (bank-spread, 8B-aligned)
    __shared__ bf16  Ps[32][72];
    __shared__ float pmax[32][4];         // per-wave max partials; reused for l at end
    __shared__ float aSt[32];

    int tid  = threadIdx.x;
    int lane = tid & 63;
    int wid  = tid >> 6;
    int l15  = lane & 15;
    int quad = lane >> 4;

    int xcd = blockIdx.x & 7;
    int b   = xcd >> 1;
    int dh  = xcd & 1;
    int i0  = (blockIdx.x >> 3) * 32;

    const bf16* Qb = Qw + (size_t)b * LL * DKK;
    const bf16* Kb = Kw + (size_t)b * LL * DKK;
    const bf16* Sb = Srel + (size_t)b * LL * LL;
    const bf16* Vb = Vt + (size_t)(dh * 256) * (BB * LL) + (size_t)b * LL;

    // persistent staging pointers (wave-local rows), bumped per iteration
    const bf16* kptr[8];
    const bf16* vptr[8];
    #pragma unroll
    for (int u = 0; u < 8; ++u) {
        int inst = wid * 8 + u;
        int j_ = inst * 2 + (lane >> 5);
        int ck = ((lane & 31) - j_) & 31;
        kptr[u] = Kb + (size_t)j_ * DKK + ck * 8;
        int d_ = inst * 8 + (lane >> 3);
        int cv = ((lane & 7) - d_) & 7;
        vptr[u] = Vb + (size_t)d_ * (BB * LL) + cv * 8;
    }

    bf16x8 Qreg[2][8];
    #pragma unroll
    for (int rt = 0; rt < 2; ++rt)
        #pragma unroll
        for (int ks = 0; ks < 8; ++ks)
            Qreg[rt][ks] = *(const bf16x8*)(Qb + (size_t)(i0 + rt * 16 + l15) * DKK
                                            + ks * 32 + quad * 8);

    f32x4 accO[2][4];
    #pragma unroll
    for (int rt = 0; rt < 2; ++rt)
        #pragma unroll
        for (int nt = 0; nt < 4; ++nt) accO[rt][nt] = 0;

    float mreg0 = -1e30f, mreg1 = -1e30f;
    float lreg0 = 0.f, lreg1 = 0.f;

    // ---- prologue: srel(0) regs first (oldest vm), then K0/V0 DMA ----
    int srow = i0 + (tid >> 3), ssg = tid & 7;
    bf16x8 srelNext = *(const bf16x8*)(Sb + (size_t)srow * LL + ssg * 8);
    const bf16* sPtr = Sb + (size_t)srow * LL + ssg * 8 + 64;
    __builtin_amdgcn_sched_barrier(0);
    #pragma unroll
    for (int u = 0; u < 8; ++u) {
        async_ld16(kptr[u], Klds + (wid * 8 + u) * 512);
        kptr[u] += 64 * DKK;
    }
    __builtin_amdgcn_sched_barrier(0);
    #pragma unroll
    for (int u = 0; u < 8; ++u) {
        async_ld16(vptr[u], Vlds + (wid * 8 + u) * 512);
        vptr[u] += 64;
    }
    __builtin_amdgcn_sched_barrier(0);
    // write SrelL[0] (compiler inserts precise vmcnt wait for srelNext)
    *(bf16x8*)&SrelL[0][(tid >> 3) * 72 + (tid & 7) * 8] = srelNext;
    asm volatile("s_waitcnt lgkmcnt(0)\ns_barrier" ::: "memory");   // srel tile 0 visible

    int jrow = wid * 16 + l15;

    for (int j0 = 0; j0 < LL; j0 += 64) {
        bool notlast = (j0 + 64 < LL);
        int p = (j0 >> 6) & 1;

        // ===== QK phase =====
        asm volatile("s_waitcnt vmcnt(8)" ::: "memory");   // K(i) staged (V(i) in flight)
        bf16x8 kf[8];
        #pragma unroll
        for (int ks = 0; ks < 8; ++ks) {
            int cp = (ks * 4 + quad + jrow) & 31;
            kf[ks] = *(const bf16x8*)&Klds[jrow * 256 + cp * 8];
        }
        asm volatile("s_waitcnt lgkmcnt(0)" ::: "memory"); // own kf reads done
        __builtin_amdgcn_sched_barrier(0);
        if (notlast) {                                     // srel(i+1) (older than K(i+1))
            srelNext = *(const bf16x8*)sPtr;
            sPtr += 64;
        }
        __builtin_amdgcn_sched_barrier(0);
        if (notlast) {                                     // K(i+1) in flight
            #pragma unroll
            for (int u = 0; u < 8; ++u) {
                async_ld16(kptr[u], Klds + (wid * 8 + u) * 512);
                kptr[u] += 64 * DKK;
            }
        }
        __builtin_amdgcn_sched_barrier(0);

        // swapped MFMA: lane gets S[q=rt*16+l15][j=wid*16+quad*4+r]
        f32x4 s0 = 0, s1 = 0;
        __builtin_amdgcn_s_setprio(1);
        #pragma unroll
        for (int ks = 0; ks < 8; ++ks) {
            s0 = __builtin_amdgcn_mfma_f32_16x16x32_bf16(kf[ks], Qreg[0][ks], s0, 0, 0, 0);
            s1 = __builtin_amdgcn_mfma_f32_16x16x32_bf16(kf[ks], Qreg[1][ks], s1, 0, 0, 0);
        }
        __builtin_amdgcn_s_setprio(0);

        // srel add (MFMA layout from SrelL[p]) + mask + scale
        bf16x4 sr0 = *(const bf16x4*)&SrelL[p][l15 * 72 + wid * 16 + quad * 4];
        bf16x4 sr1 = *(const bf16x4*)&SrelL[p][(16 + l15) * 72 + wid * 16 + quad * 4];
        int jb = j0 + wid * 16 + quad * 4;
        float v0[4], v1[4];
        #pragma unroll
        for (int r = 0; r < 4; ++r) {
            float a0 = (jb + r == i0 + l15 + 1)      ? 0.f : (float)sr0[r];
            float a1 = (jb + r == i0 + 16 + l15 + 1) ? 0.f : (float)sr1[r];
            v0[r] = (s0[r] + a0) * 0.0625f;
            v1[r] = (s1[r] + a1) * 0.0625f;
        }
        // in-wave max over this wave's 16 j's (in-lane 4 + quad butterfly)
        float m0 = fmaxf(fmaxf(v0[0], v0[1]), fmaxf(v0[2], v0[3]));
        float m1 = fmaxf(fmaxf(v1[0], v1[1]), fmaxf(v1[2], v1[3]));
        m0 = fmaxf(m0, __shfl_xor(m0, 16)); m0 = fmaxf(m0, __shfl_xor(m0, 32));
        m1 = fmaxf(m1, __shfl_xor(m1, 16)); m1 = fmaxf(m1, __shfl_xor(m1, 32));
        if (quad == 0) { pmax[l15][wid] = m0; pmax[16 + l15][wid] = m1; }
        asm volatile("s_waitcnt lgkmcnt(0)\ns_barrier" ::: "memory");   // b2: max handoff

        // ===== softmax (in-register) =====
        f32x4 pm0 = *(const f32x4*)&pmax[l15][0];
        f32x4 pm1 = *(const f32x4*)&pmax[16 + l15][0];
        float mf0 = fmaxf(fmaxf(fmaxf(pm0[0], pm0[1]), fmaxf(pm0[2], pm0[3])), mreg0);
        float mf1 = fmaxf(fmaxf(fmaxf(pm1[0], pm1[1]), fmaxf(pm1[2], pm1[3])), mreg1);
        float al0 = __expf(mreg0 - mf0); mreg0 = mf0;
        float al1 = __expf(mreg1 - mf1); mreg1 = mf1;
        // stage srel(i+1) into the other buffer (off critical path)
        if (notlast)
            *(bf16x8*)&SrelL[p ^ 1][(tid >> 3) * 72 + (tid & 7) * 8] = srelNext;
        float ps0 = 0.f, ps1 = 0.f;
        bf16x4 pv0, pv1;
        #pragma unroll
        for (int r = 0; r < 4; ++r) {
            float e0 = __expf(v0[r] - mf0); ps0 += e0; pv0[r] = (bf16)e0;
            float e1 = __expf(v1[r] - mf1); ps1 += e1; pv1[r] = (bf16)e1;
        }
        ps0 += __shfl_xor(ps0, 16); ps0 += __shfl_xor(ps0, 32);
        ps1 += __shfl_xor(ps1, 16); ps1 += __shfl_xor(ps1, 32);
        lreg0 = al0 * lreg0 + ps0;
        lreg1 = al1 * lreg1 + ps1;
        *(bf16x4*)&Ps[l15][wid * 16 + quad * 4]      = pv0;
        *(bf16x4*)&Ps[16 + l15][wid * 16 + quad * 4] = pv1;
        if (wid == 0 && quad == 0) { aSt[l15] = al0; aSt[16 + l15] = al1; }
        asm volatile("s_waitcnt lgkmcnt(0)\ns_barrier" ::: "memory");   // b3: Ps handoff

        // ===== PV phase =====
        if (notlast) asm volatile("s_waitcnt vmcnt(8)" ::: "memory");   // V(i) staged
        else         asm volatile("s_waitcnt vmcnt(0)" ::: "memory");
        bf16x8 aF[2][2];
        #pragma unroll
        for (int rt = 0; rt < 2; ++rt)
            #pragma unroll
            for (int kk = 0; kk < 2; ++kk)
                aF[rt][kk] = *(const bf16x8*)&Ps[rt * 16 + l15][kk * 32 + quad * 8];
        float ar[2][4];
        #pragma unroll
        for (int rt = 0; rt < 2; ++rt)
            #pragma unroll
            for (int r = 0; r < 4; ++r) ar[rt][r] = aSt[rt * 16 + quad * 4 + r];
        bf16x8 vf[4][2];
        #pragma unroll
        for (int nt = 0; nt < 4; ++nt) {
            int dd = wid * 64 + nt * 16 + l15;
            int c0 = (quad + dd) & 7;
            int c1 = (4 + quad + dd) & 7;
            vf[nt][0] = *(const bf16x8*)&Vlds[dd * 64 + c0 * 8];
            vf[nt][1] = *(const bf16x8*)&Vlds[dd * 64 + c1 * 8];
        }
        asm volatile("s_waitcnt lgkmcnt(0)" ::: "memory");
        __builtin_amdgcn_sched_barrier(0);
        if (notlast) {                                     // V(i+1) in flight
            #pragma unroll
            for (int u = 0; u < 8; ++u) {
                async_ld16(vptr[u], Vlds + (wid * 8 + u) * 512);
                vptr[u] += 64;
            }
        }
        __builtin_amdgcn_sched_barrier(0);
        __builtin_amdgcn_s_setprio(1);
        #pragma unroll
        for (int nt = 0; nt < 4; ++nt) {
            #pragma unroll
            for (int rt = 0; rt < 2; ++rt) {
                f32x4 o = accO[rt][nt];
                o[0] *= ar[rt][0]; o[1] *= ar[rt][1];
                o[2] *= ar[rt][2]; o[3] *= ar[rt][3];
                o = __builtin_amdgcn_mfma_f32_16x16x32_bf16(aF[rt][0], vf[nt][0], o, 0, 0, 0);
                o = __builtin_amdgcn_mfma_f32_16x16x32_bf16(aF[rt][1], vf[nt][1], o, 0, 0, 0);
                accO[rt][nt] = o;
            }
        }
        __builtin_amdgcn_s_setprio(0);
    }

    // ---- final l merge: per-wave partials summed (valid: shared alpha seq) ----
    if (quad == 0) { pmax[l15][wid] = lreg0; pmax[16 + l15][wid] = lreg1; }
    asm volatile("s_waitcnt lgkmcnt(0)\ns_barrier" ::: "memory");
    float lr[2][4];
    #pragma unroll
    for (int rt = 0; rt < 2; ++rt)
        #pragma unroll
        for (int r = 0; r < 4; ++r) {
            f32x4 lp = *(const f32x4*)&pmax[rt * 16 + quad * 4 + r][0];
            lr[rt][r] = 1.f / (lp[0] + lp[1] + lp[2] + lp[3]);
        }
    #pragma unroll
    for (int rt = 0; rt < 2; ++rt)
        #pragma unroll
        for (int nt = 0; nt < 4; ++nt)
            #pragma unroll
            for (int r = 0; r < 4; ++r) {
                int i = i0 + rt * 16 + quad * 4 + r;
                int d = dh * 256 + wid * 64 + nt * 16 + l15;
                out[((size_t)b * LL + i) * DD + d] = accO[rt][nt][r] * lr[rt][r];
            }
}

extern "C" void kernel_launch(void* const* d_in, const int* in_sizes, int n_in,
                              void* d_out, int out_size, void* d_ws, size_t ws_size,
                              hipStream_t stream) {
    const float* inQ = (const float*)d_in[0];
    const float* inK = (const float*)d_in[1];
    const float* inV = (const float*)d_in[2];
    const float* Wq  = (const float*)d_in[3];
    const float* Wk  = (const float*)d_in[4];
    const float* Wv  = (const float*)d_in[5];
    const float* E   = (const float*)d_in[6];
    float* out = (float*)d_out;

    char* ws = (char*)d_ws;
    bf16* Qw   = (bf16*)(ws);                         // 4 MB  [B*L][DK]
    bf16* Kw   = (bf16*)(ws + ((size_t)4  << 20));    // 4 MB  [B*L][DK]
    bf16* Vt   = (bf16*)(ws + ((size_t)8  << 20));    // 8 MB  [D][B*L]
    bf16* SrelW= (bf16*)(ws + ((size_t)16 << 20));    // 32 MB [B,L,L] skewed
    bf16* Xq   = (bf16*)(ws + ((size_t)16 << 20));    // 8 MB  (transient)
    bf16* Xk   = (bf16*)(ws + ((size_t)24 << 20));    // 8 MB
    bf16* Xv   = (bf16*)(ws + ((size_t)32 << 20));    // 8 MB
    bf16* WqT  = (bf16*)(ws + ((size_t)48 << 20));            // [DK][D]
    bf16* WkT  = (bf16*)(ws + ((size_t)48 << 20) + 262144);   // [DK][D]
    bf16* WvT  = (bf16*)(ws + ((size_t)48 << 20) + 524288);   // [D][D]
    bf16* Eb   = (bf16*)(ws + ((size_t)49 << 20));            // [L][DK]

    conv3_f32_bf16<<<dim3(4096, 3), 256, 0, stream>>>(inQ, inK, inV, Xq, Xk, Xv,
                                                      (BB * LL * DD) / 4);
    prep_misc<<<dim3(1024, 4), 256, 0, stream>>>(E, Wq, Wk, Wv, Eb, WqT, WkT, WvT);

    // Q and K GEMMs fused via blockIdx.y: M=8192 N=256 K=512
    gemm128<0, 0><<<dim3(2 * 64, 2),  256, 0, stream>>>(Xq, WqT, Qw, DKK, DD,
                                                        4194304L, 131072L, 2097152L);
    // Vt = (Xv·Wv^T')^T written directly (fused transpose): M=8192 N=512 K=512
    gemm128<0, 1><<<dim3(4 * 64, 1),  256, 0, stream>>>(Xv, WvT, Vt, DD, DD, 0, 0, 0);
    // Srel (skewed) = skew(Q·E^T): per-batch M=N=2048 K=256
    gemm128<1, 0><<<dim3(16 * 16, BB), 256, 0, stream>>>(Qw, Eb, SrelW, LL, DKK,
                                                         (long)LL * DKK, 0, (long)LL * LL);
    attn_kernel<<<dim3(BB * 64 * 2), 256, 0, stream>>>(Qw, Kw, Vt, SrelW, out);
}

// Round 8
// 229.723 us; speedup vs baseline: 1.2602x; 1.0216x over previous
//
#include <hip/hip_runtime.h>
#include <hip/hip_bf16.h>

#define BB 4
#define LL 2048
#define DD 512
#define DKK 256

typedef __bf16 bf16;
typedef __bf16 bf16x4 __attribute__((ext_vector_type(4)));
typedef __bf16 bf16x8 __attribute__((ext_vector_type(8)));
typedef float f32x4 __attribute__((ext_vector_type(4)));

__device__ __forceinline__ void async_ld16(const bf16* g, bf16* l) {
    __builtin_amdgcn_global_load_lds(
        (const __attribute__((address_space(1))) void*)g,
        (__attribute__((address_space(3))) void*)l, 16, 0, 0);
}

// fused bf16 conversion of the three [B,L,D] activations (one launch)
__global__ void conv3_f32_bf16(const float* __restrict__ a, const float* __restrict__ bq,
                               const float* __restrict__ c,
                               bf16* __restrict__ oa, bf16* __restrict__ ob,
                               bf16* __restrict__ oc, int n4) {
    const float* in = (blockIdx.y == 0) ? a : (blockIdx.y == 1) ? bq : c;
    bf16* out = (blockIdx.y == 0) ? oa : (blockIdx.y == 1) ? ob : oc;
    int i = blockIdx.x * 256 + threadIdx.x;
    if (i < n4) {
        f32x4 v = *(const f32x4*)(in + (size_t)i * 4);
        bf16x4 o;
        #pragma unroll
        for (int j = 0; j < 4; ++j) o[j] = (bf16)v[j];
        *(bf16x4*)(out + (size_t)i * 4) = o;
    }
}

// merged prep: E conversion + Wq/Wk/Wv transposes in one launch (blockIdx.y)
__global__ void prep_misc(const float* __restrict__ E, const float* __restrict__ Wq,
                          const float* __restrict__ Wk, const float* __restrict__ Wv,
                          bf16* __restrict__ Eb, bf16* __restrict__ WqT,
                          bf16* __restrict__ WkT, bf16* __restrict__ WvT) {
    int y = blockIdx.y;
    int idx = blockIdx.x * 256 + threadIdx.x;
    if (y == 0) {
        if (idx < (LL * DKK) / 4) {
            f32x4 v = *(const f32x4*)(E + (size_t)idx * 4);
            bf16x4 o;
            #pragma unroll
            for (int j = 0; j < 4; ++j) o[j] = (bf16)v[j];
            *(bf16x4*)(Eb + (size_t)idx * 4) = o;
        }
    } else if (y == 1) {
        if (idx < DD * DKK) { int r = idx / DKK, c = idx % DKK; WqT[(size_t)c * DD + r] = (bf16)Wq[idx]; }
    } else if (y == 2) {
        if (idx < DD * DKK) { int r = idx / DKK, c = idx % DKK; WkT[(size_t)c * DD + r] = (bf16)Wk[idx]; }
    } else {
        if (idx < DD * DD)  { int r = idx / DD,  c = idx % DD;  WvT[(size_t)c * DD + r] = (bf16)Wv[idx]; }
    }
}

// Merged Q/K/V projection GEMM: one 512-block full-GPU launch.
//   bid <128: Q = Xq·WqT' (N=256)   128-255: K = Xk·WkT' (N=256)
//   bid>=256: Vt = (Xv·WvT')^T (N=512), written transposed via tbuf bounce.
// Previously these ran as two 256-block launches (each only half the GPU).
// Main loop identical to the m97-style gemm128; mode is block-uniform.
__launch_bounds__(256, 2)
__global__ void gemm_qkv(const bf16* __restrict__ Xq, const bf16* __restrict__ WqT,
                         bf16* __restrict__ Qw,
                         const bf16* __restrict__ Xk, const bf16* __restrict__ WkT,
                         bf16* __restrict__ Kw,
                         const bf16* __restrict__ Xv, const bf16* __restrict__ WvT,
                         bf16* __restrict__ Vt)
{
    __shared__ bf16 Als[128 * 32];
    __shared__ bf16 Bls[128 * 32];
    __shared__ bf16 tbuf[64 * 136];

    int tid  = threadIdx.x;
    int lane = tid & 63;
    int wid  = tid >> 6;
    int l15  = lane & 15;
    int quad = lane >> 4;

    int bid  = blockIdx.x;
    int mode = (bid < 128) ? 0 : (bid < 256) ? 1 : 2;
    int idx  = bid - ((mode == 0) ? 0 : (mode == 1) ? 128 : 256);
    int nb   = (mode == 2) ? 4 : 2;
    int gx = idx % nb;
    int gy = idx / nb;
    int N  = (mode == 2) ? DD : DKK;
    const bf16* A  = (mode == 0) ? Xq  : (mode == 1) ? Xk  : Xv;
    const bf16* Bw = (mode == 0) ? WqT : (mode == 1) ? WkT : WvT;
    const int K = DD;

    const bf16* Ab = A + (size_t)gy * 128 * K;
    const bf16* Bb = Bw + (size_t)gx * 128 * K;

    int rl = lane >> 2;
    int sl = lane & 3;
    int half = wid & 1;
    const bf16* gsrc = (wid < 2) ? Ab : Bb;
    bf16* ldst = (wid < 2) ? Als : Bls;

    const bf16* gptr[4];
    #pragma unroll
    for (int u = 0; u < 4; ++u) {
        int inst = half * 4 + u;
        int row  = inst * 16 + rl;
        int c    = (sl - (row >> 1)) & 3;
        gptr[u] = gsrc + (size_t)row * K + c * 8;
    }

    f32x4 acc[4][4];
    #pragma unroll
    for (int i = 0; i < 4; ++i)
        #pragma unroll
        for (int j = 0; j < 4; ++j) acc[i][j] = 0;

    for (int k0 = 0; k0 < K; k0 += 32) {
        #pragma unroll
        for (int u = 0; u < 4; ++u) {
            async_ld16(gptr[u], ldst + (half * 4 + u) * 512);
            gptr[u] += 32;
        }
        __syncthreads();
        bf16x8 fA[4], fB[4];
        #pragma unroll
        for (int rt = 0; rt < 4; ++rt) {
            int row = (wid & 1) * 64 + rt * 16 + l15;
            int s   = (quad + (row >> 1)) & 3;
            fA[rt] = *(const bf16x8*)&Als[row * 32 + s * 8];
        }
        #pragma unroll
        for (int ct = 0; ct < 4; ++ct) {
            int col = (wid >> 1) * 64 + ct * 16 + l15;
            int s   = (quad + (col >> 1)) & 3;
            fB[ct] = *(const bf16x8*)&Bls[col * 32 + s * 8];
        }
        #pragma unroll
        for (int rt = 0; rt < 4; ++rt)
            #pragma unroll
            for (int ct = 0; ct < 4; ++ct)
                acc[rt][ct] = __builtin_amdgcn_mfma_f32_16x16x32_bf16(
                                  fA[rt], fB[ct], acc[rt][ct], 0, 0, 0);
        __syncthreads();
    }

    if (mode == 2) {
        // C^T -> Vt[n][m] via tbuf bounce (stride 136 keeps b128 rows 16B-aligned)
        #pragma unroll
        for (int p = 0; p < 2; ++p) {
            if ((wid >> 1) == p) {
                #pragma unroll
                for (int rt = 0; rt < 4; ++rt)
                    #pragma unroll
                    for (int ct = 0; ct < 4; ++ct)
                        #pragma unroll
                        for (int r = 0; r < 4; ++r)
                            tbuf[(ct * 16 + l15) * 136
                                 + (wid & 1) * 64 + rt * 16 + quad * 4 + r]
                                = (bf16)acc[rt][ct][r];
            }
            __syncthreads();
            int row = tid >> 2, c0 = (tid & 3) * 32;
            bf16* dst = Vt + (size_t)(gx * 128 + p * 64 + row) * (BB * LL)
                           + (size_t)gy * 128 + c0;
            #pragma unroll
            for (int q = 0; q < 4; ++q)
                *(bf16x8*)(dst + q * 8) = *(const bf16x8*)&tbuf[row * 136 + c0 + q * 8];
            __syncthreads();
        }
    } else {
        bf16* Cb = (mode == 0) ? Qw : Kw;
        int m0 = gy * 128 + (wid & 1) * 64;
        int n0 = gx * 128 + (wid >> 1) * 64;
        #pragma unroll
        for (int rt = 0; rt < 4; ++rt)
            #pragma unroll
            for (int ct = 0; ct < 4; ++ct)
                #pragma unroll
                for (int r = 0; r < 4; ++r) {
                    int m = m0 + rt * 16 + quad * 4 + r;
                    int n = n0 + ct * 16 + l15;
                    Cb[(size_t)m * N + n] = (bf16)acc[rt][ct][r];
                }
    }
}

// Srel GEMM (skewed scatter epilogue), unchanged from R13.
__launch_bounds__(256, 2)
__global__ void gemm_srel(const bf16* __restrict__ A, const bf16* __restrict__ B,
                          bf16* __restrict__ C, long aStride, long cStride)
{
    __shared__ bf16 Als[128 * 32];
    __shared__ bf16 Bls[128 * 32];

    int tid  = threadIdx.x;
    int lane = tid & 63;
    int wid  = tid >> 6;
    int l15  = lane & 15;
    int quad = lane >> 4;
    const int N = LL, K = DKK;
    int nb = N >> 7;
    int gx = blockIdx.x % nb;
    int gy = blockIdx.x / nb;

    const bf16* Ab = A + (size_t)blockIdx.y * aStride + (size_t)gy * 128 * K;
    const bf16* Bb = B + (size_t)gx * 128 * K;

    int rl = lane >> 2;
    int sl = lane & 3;
    int half = wid & 1;
    const bf16* gsrc = (wid < 2) ? Ab : Bb;
    bf16* ldst = (wid < 2) ? Als : Bls;

    const bf16* gptr[4];
    #pragma unroll
    for (int u = 0; u < 4; ++u) {
        int inst = half * 4 + u;
        int row  = inst * 16 + rl;
        int c    = (sl - (row >> 1)) & 3;
        gptr[u] = gsrc + (size_t)row * K + c * 8;
    }

    f32x4 acc[4][4];
    #pragma unroll
    for (int i = 0; i < 4; ++i)
        #pragma unroll
        for (int j = 0; j < 4; ++j) acc[i][j] = 0;

    for (int k0 = 0; k0 < K; k0 += 32) {
        #pragma unroll
        for (int u = 0; u < 4; ++u) {
            async_ld16(gptr[u], ldst + (half * 4 + u) * 512);
            gptr[u] += 32;
        }
        __syncthreads();
        bf16x8 fA[4], fB[4];
        #pragma unroll
        for (int rt = 0; rt < 4; ++rt) {
            int row = (wid & 1) * 64 + rt * 16 + l15;
            int s   = (quad + (row >> 1)) & 3;
            fA[rt] = *(const bf16x8*)&Als[row * 32 + s * 8];
        }
        #pragma unroll
        for (int ct = 0; ct < 4; ++ct) {
            int col = (wid >> 1) * 64 + ct * 16 + l15;
            int s   = (quad + (col >> 1)) & 3;
            fB[ct] = *(const bf16x8*)&Bls[col * 32 + s * 8];
        }
        #pragma unroll
        for (int rt = 0; rt < 4; ++rt)
            #pragma unroll
            for (int ct = 0; ct < 4; ++ct)
                acc[rt][ct] = __builtin_amdgcn_mfma_f32_16x16x32_bf16(
                                  fA[rt], fB[ct], acc[rt][ct], 0, 0, 0);
        __syncthreads();
    }

    bf16* Cb = C + (size_t)blockIdx.y * cStride;
    int m0 = gy * 128 + (wid & 1) * 64;
    int n0 = gx * 128 + (wid >> 1) * 64;
    #pragma unroll
    for (int rt = 0; rt < 4; ++rt)
        #pragma unroll
        for (int ct = 0; ct < 4; ++ct)
            #pragma unroll
            for (int r = 0; r < 4; ++r) {
                int row = m0 + rt * 16 + quad * 4 + r;
                int c   = n0 + ct * 16 + l15;
                bool lower = (c >= LL - 1 - row);
                int dr = lower ? row : row - 1;
                int dc = lower ? c - (LL - 1 - row) : c + row + 1;
                if (lower || row >= 1)
                    Cb[(size_t)dr * LL + dc] = (bf16)acc[rt][ct][r];
            }
}

// Fused attention R15 = R14 + DEFERRED-PV OVERLAP.  PV for tile i-1 executes
// inside iteration i's QK phase (before b2): the rescale recurrence
// O = O*alpha_{i-1} + P_{i-1}V_{i-1} needs only softmax(i-1) outputs, all
// ready pre-b2(i).  The per-iteration serial chain loses the whole PV slot;
// PV LDS-reads overlap the QK MFMA chain and PV MFMAs overlap the softmax
// VALU.  Buffering audit: Ps/aSt/SrelL all SINGLE-buffered -- each write
// (post-b2(i)) and read (pre-b2(i+1)) pair is RAW-guarded by b3(i) and
// WAR-guarded by b2(i+1).  (R14's SrelL double-buffer was unnecessary.)
// vmcnt choreography (per-wave stream order: srel(i+1), K(i+1), V(i)):
//   top-of-iter: vmcnt(8)  = K(i) done, V(i-1) in flight   [iter0: vmcnt(0)]
//   PV slot:     vmcnt(9)  = V(i-1) done, srel+K(i+1) fly  [last: vmcnt(0)]
//   V(i) issued EVERY iter (consumed by epilogue PV(31) after the loop).
// Iter 0 skips PV compute (Vlds holds garbage; P=0 would still propagate
// NaN from garbage bf16 patterns).  Barriers: 2 raw lgkm-only/iter.
__launch_bounds__(256, 2)
__global__ void attn_kernel(const bf16* __restrict__ Qw, const bf16* __restrict__ Kw,
                            const bf16* __restrict__ Vt, const bf16* __restrict__ Srel,
                            float* __restrict__ out)
{
    __shared__ bf16  Klds[64 * 256];
    __shared__ bf16  Vlds[256 * 64];
    __shared__ bf16  SrelL[32 * 72];      // single-buffered (see audit above)
    __shared__ bf16  Ps[32][72];
    __shared__ float pmax[32][4];         // max partials; reused for l at end
    __shared__ float aSt[32];

    int tid  = threadIdx.x;
    int lane = tid & 63;
    int wid  = tid >> 6;
    int l15  = lane & 15;
    int quad = lane >> 4;

    int xcd = blockIdx.x & 7;
    int b   = xcd >> 1;
    int dh  = xcd & 1;
    int i0  = (blockIdx.x >> 3) * 32;

    const bf16* Qb = Qw + (size_t)b * LL * DKK;
    const bf16* Kb = Kw + (size_t)b * LL * DKK;
    const bf16* Sb = Srel + (size_t)b * LL * LL;
    const bf16* Vb = Vt + (size_t)(dh * 256) * (BB * LL) + (size_t)b * LL;

    const bf16* kptr[8];
    const bf16* vptr[8];
    #pragma unroll
    for (int u = 0; u < 8; ++u) {
        int inst = wid * 8 + u;
        int j_ = inst * 2 + (lane >> 5);
        int ck = ((lane & 31) - j_) & 31;
        kptr[u] = Kb + (size_t)j_ * DKK + ck * 8;
        int d_ = inst * 8 + (lane >> 3);
        int cv = ((lane & 7) - d_) & 7;
        vptr[u] = Vb + (size_t)d_ * (BB * LL) + cv * 8;
    }

    bf16x8 Qreg[2][8];
    #pragma unroll
    for (int rt = 0; rt < 2; ++rt)
        #pragma unroll
        for (int ks = 0; ks < 8; ++ks)
            Qreg[rt][ks] = *(const bf16x8*)(Qb + (size_t)(i0 + rt * 16 + l15) * DKK
                                            + ks * 32 + quad * 8);

    f32x4 accO[2][4];
    #pragma unroll
    for (int rt = 0; rt < 2; ++rt)
        #pragma unroll
        for (int nt = 0; nt < 4; ++nt) accO[rt][nt] = 0;

    float mreg0 = -1e30f, mreg1 = -1e30f;
    float lreg0 = 0.f, lreg1 = 0.f;

    // drain Qreg loads before the counted staging stream starts
    asm volatile("s_waitcnt vmcnt(0)" ::: "memory");

    // ---- prologue: srel(0) load, K(0) DMA, SrelL write (waits srel only) ----
    int srow = i0 + (tid >> 3), ssg = tid & 7;
    bf16x8 srelNext = *(const bf16x8*)(Sb + (size_t)srow * LL + ssg * 8);
    const bf16* sPtr = Sb + (size_t)srow * LL + ssg * 8 + 64;
    __builtin_amdgcn_sched_barrier(0);
    #pragma unroll
    for (int u = 0; u < 8; ++u) {
        async_ld16(kptr[u], Klds + (wid * 8 + u) * 512);
        kptr[u] += 64 * DKK;
    }
    __builtin_amdgcn_sched_barrier(0);
    *(bf16x8*)&SrelL[(tid >> 3) * 72 + (tid & 7) * 8] = srelNext;
    asm volatile("s_waitcnt lgkmcnt(0)\ns_barrier" ::: "memory");   // srel tile 0 visible

    int jrow = wid * 16 + l15;

    for (int j0 = 0; j0 < LL; j0 += 64) {
        bool notlast = (j0 + 64 < LL);

        // ===== QK phase =====
        if (j0 == 0) asm volatile("s_waitcnt vmcnt(0)" ::: "memory");  // K(0) done
        else         asm volatile("s_waitcnt vmcnt(8)" ::: "memory");  // K(i) done, V(i-1) flies
        bf16x8 kf[8];
        #pragma unroll
        for (int ks = 0; ks < 8; ++ks) {
            int cp = (ks * 4 + quad + jrow) & 31;
            kf[ks] = *(const bf16x8*)&Klds[jrow * 256 + cp * 8];
        }
        asm volatile("s_waitcnt lgkmcnt(0)" ::: "memory"); // own kf reads done
        __builtin_amdgcn_sched_barrier(0);
        if (notlast) {                                     // srel(i+1) in flight
            srelNext = *(const bf16x8*)sPtr;
            sPtr += 64;
        }
        __builtin_amdgcn_sched_barrier(0);
        if (notlast) {                                     // K(i+1) in flight
            #pragma unroll
            for (int u = 0; u < 8; ++u) {
                async_ld16(kptr[u], Klds + (wid * 8 + u) * 512);
                kptr[u] += 64 * DKK;
            }
        }
        __builtin_amdgcn_sched_barrier(0);

        // swapped MFMA: lane gets S[q=rt*16+l15][j=wid*16+quad*4+r]
        f32x4 s0 = 0, s1 = 0;
        __builtin_amdgcn_s_setprio(1);
        #pragma unroll
        for (int ks = 0; ks < 8; ++ks) {
            s0 = __builtin_amdgcn_mfma_f32_16x16x32_bf16(kf[ks], Qreg[0][ks], s0, 0, 0, 0);
            s1 = __builtin_amdgcn_mfma_f32_16x16x32_bf16(kf[ks], Qreg[1][ks], s1, 0, 0, 0);
        }
        __builtin_amdgcn_s_setprio(0);

        // ===== deferred PV slot: tile i-1 (overlaps QK chain + softmax) =====
        if (notlast) asm volatile("s_waitcnt vmcnt(9)" ::: "memory");  // V(i-1) done
        else         asm volatile("s_waitcnt vmcnt(0)" ::: "memory");
        if (j0) {
            bf16x8 aF[2][2];
            #pragma unroll
            for (int rt = 0; rt < 2; ++rt)
                #pragma unroll
                for (int kk = 0; kk < 2; ++kk)
                    aF[rt][kk] = *(const bf16x8*)&Ps[rt * 16 + l15][kk * 32 + quad * 8];
            float ar[2][4];
            #pragma unroll
            for (int rt = 0; rt < 2; ++rt)
                #pragma unroll
                for (int r = 0; r < 4; ++r) ar[rt][r] = aSt[rt * 16 + quad * 4 + r];
            bf16x8 vf[4][2];
            #pragma unroll
            for (int nt = 0; nt < 4; ++nt) {
                int dd = wid * 64 + nt * 16 + l15;
                int c0 = (quad + dd) & 7;
                int c1 = (4 + quad + dd) & 7;
                vf[nt][0] = *(const bf16x8*)&Vlds[dd * 64 + c0 * 8];
                vf[nt][1] = *(const bf16x8*)&Vlds[dd * 64 + c1 * 8];
            }
            asm volatile("s_waitcnt lgkmcnt(0)" ::: "memory");  // own Vlds/Ps reads done
            __builtin_amdgcn_sched_barrier(0);
            #pragma unroll
            for (int u = 0; u < 8; ++u) {                  // V(i) in flight (wave-local)
                async_ld16(vptr[u], Vlds + (wid * 8 + u) * 512);
                vptr[u] += 64;
            }
            __builtin_amdgcn_sched_barrier(0);
            __builtin_amdgcn_s_setprio(1);
            #pragma unroll
            for (int nt = 0; nt < 4; ++nt) {
                #pragma unroll
                for (int rt = 0; rt < 2; ++rt) {
                    f32x4 o = accO[rt][nt];
                    o[0] *= ar[rt][0]; o[1] *= ar[rt][1];
                    o[2] *= ar[rt][2]; o[3] *= ar[rt][3];
                    o = __builtin_amdgcn_mfma_f32_16x16x32_bf16(aF[rt][0], vf[nt][0], o, 0, 0, 0);
                    o = __builtin_amdgcn_mfma_f32_16x16x32_bf16(aF[rt][1], vf[nt][1], o, 0, 0, 0);
                    accO[rt][nt] = o;
                }
            }
            __builtin_amdgcn_s_setprio(0);
        } else {
            // iter 0: no PV yet; just stage V(0) (Vlds has no readers)
            #pragma unroll
            for (int u = 0; u < 8; ++u) {
                async_ld16(vptr[u], Vlds + (wid * 8 + u) * 512);
                vptr[u] += 64;
            }
        }

        // ===== v-compute (QK results + SrelL tile i) =====
        bf16x4 sr0 = *(const bf16x4*)&SrelL[l15 * 72 + wid * 16 + quad * 4];
        bf16x4 sr1 = *(const bf16x4*)&SrelL[(16 + l15) * 72 + wid * 16 + quad * 4];
        int jb = j0 + wid * 16 + quad * 4;
        float v0[4], v1[4];
        #pragma unroll
        for (int r = 0; r < 4; ++r) {
            float a0 = (jb + r == i0 + l15 + 1)      ? 0.f : (float)sr0[r];
            float a1 = (jb + r == i0 + 16 + l15 + 1) ? 0.f : (float)sr1[r];
            v0[r] = (s0[r] + a0) * 0.0625f;
            v1[r] = (s1[r] + a1) * 0.0625f;
        }
        float m0 = fmaxf(fmaxf(v0[0], v0[1]), fmaxf(v0[2], v0[3]));
        float m1 = fmaxf(fmaxf(v1[0], v1[1]), fmaxf(v1[2], v1[3]));
        m0 = fmaxf(m0, __shfl_xor(m0, 16)); m0 = fmaxf(m0, __shfl_xor(m0, 32));
        m1 = fmaxf(m1, __shfl_xor(m1, 16)); m1 = fmaxf(m1, __shfl_xor(m1, 32));
        if (quad == 0) { pmax[l15][wid] = m0; pmax[16 + l15][wid] = m1; }
        asm volatile("s_waitcnt lgkmcnt(0)\ns_barrier" ::: "memory");   // b2: max handoff

        // ===== softmax (in-register) =====
        f32x4 pm0 = *(const f32x4*)&pmax[l15][0];
        f32x4 pm1 = *(const f32x4*)&pmax[16 + l15][0];
        float mf0 = fmaxf(fmaxf(fmaxf(pm0[0], pm0[1]), fmaxf(pm0[2], pm0[3])), mreg0);
        float mf1 = fmaxf(fmaxf(fmaxf(pm1[0], pm1[1]), fmaxf(pm1[2], pm1[3])), mreg1);
        float al0 = __expf(mreg0 - mf0); mreg0 = mf0;
        float al1 = __expf(mreg1 - mf1); mreg1 = mf1;
        if (notlast)                                        // stage srel(i+1)
            *(bf16x8*)&SrelL[(tid >> 3) * 72 + (tid & 7) * 8] = srelNext;
        float ps0 = 0.f, ps1 = 0.f;
        bf16x4 pv0, pv1;
        #pragma unroll
        for (int r = 0; r < 4; ++r) {
            float e0 = __expf(v0[r] - mf0); ps0 += e0; pv0[r] = (bf16)e0;
            float e1 = __expf(v1[r] - mf1); ps1 += e1; pv1[r] = (bf16)e1;
        }
        ps0 += __shfl_xor(ps0, 16); ps0 += __shfl_xor(ps0, 32);
        ps1 += __shfl_xor(ps1, 16); ps1 += __shfl_xor(ps1, 32);
        lreg0 = al0 * lreg0 + ps0;
        lreg1 = al1 * lreg1 + ps1;
        *(bf16x4*)&Ps[l15][wid * 16 + quad * 4]      = pv0;
        *(bf16x4*)&Ps[16 + l15][wid * 16 + quad * 4] = pv1;
        if (wid == 0 && quad == 0) { aSt[l15] = al0; aSt[16 + l15] = al1; }
        asm volatile("s_waitcnt lgkmcnt(0)\ns_barrier" ::: "memory");   // b3: Ps handoff
    }

    // ===== epilogue PV(31) =====
    asm volatile("s_waitcnt vmcnt(0)" ::: "memory");        // V(31) staged
    {
        bf16x8 aF[2][2];
        #pragma unroll
        for (int rt = 0; rt < 2; ++rt)
            #pragma unroll
            for (int kk = 0; kk < 2; ++kk)
                aF[rt][kk] = *(const bf16x8*)&Ps[rt * 16 + l15][kk * 32 + quad * 8];
        float ar[2][4];
        #pragma unroll
        for (int rt = 0; rt < 2; ++rt)
            #pragma unroll
            for (int r = 0; r < 4; ++r) ar[rt][r] = aSt[rt * 16 + quad * 4 + r];
        bf16x8 vf[4][2];
        #pragma unroll
        for (int nt = 0; nt < 4; ++nt) {
            int dd = wid * 64 + nt * 16 + l15;
            int c0 = (quad + dd) & 7;
            int c1 = (4 + quad + dd) & 7;
            vf[nt][0] = *(const bf16x8*)&Vlds[dd * 64 + c0 * 8];
            vf[nt][1] = *(const bf16x8*)&Vlds[dd * 64 + c1 * 8];
        }
        #pragma unroll
        for (int nt = 0; nt < 4; ++nt) {
            #pragma unroll
            for (int rt = 0; rt < 2; ++rt) {
                f32x4 o = accO[rt][nt];
                o[0] *= ar[rt][0]; o[1] *= ar[rt][1];
                o[2] *= ar[rt][2]; o[3] *= ar[rt][3];
                o = __builtin_amdgcn_mfma_f32_16x16x32_bf16(aF[rt][0], vf[nt][0], o, 0, 0, 0);
                o = __builtin_amdgcn_mfma_f32_16x16x32_bf16(aF[rt][1], vf[nt][1], o, 0, 0, 0);
                accO[rt][nt] = o;
            }
        }
    }

    // ---- final l merge: per-wave partials summed (shared alpha sequence) ----
    if (quad == 0) { pmax[l15][wid] = lreg0; pmax[16 + l15][wid] = lreg1; }
    asm volatile("s_waitcnt lgkmcnt(0)\ns_barrier" ::: "memory");
    float lr[2][4];
    #pragma unroll
    for (int rt = 0; rt < 2; ++rt)
        #pragma unroll
        for (int r = 0; r < 4; ++r) {
            f32x4 lp = *(const f32x4*)&pmax[rt * 16 + quad * 4 + r][0];
            lr[rt][r] = 1.f / (lp[0] + lp[1] + lp[2] + lp[3]);
        }
    #pragma unroll
    for (int rt = 0; rt < 2; ++rt)
        #pragma unroll
        for (int nt = 0; nt < 4; ++nt)
            #pragma unroll
            for (int r = 0; r < 4; ++r) {
                int i = i0 + rt * 16 + quad * 4 + r;
                int d = dh * 256 + wid * 64 + nt * 16 + l15;
                out[((size_t)b * LL + i) * DD + d] = accO[rt][nt][r] * lr[rt][r];
            }
}

extern "C" void kernel_launch(void* const* d_in, const int* in_sizes, int n_in,
                              void* d_out, int out_size, void* d_ws, size_t ws_size,
                              hipStream_t stream) {
    const float* inQ = (const float*)d_in[0];
    const float* inK = (const float*)d_in[1];
    const float* inV = (const float*)d_in[2];
    const float* Wq  = (const float*)d_in[3];
    const float* Wk  = (const float*)d_in[4];
    const float* Wv  = (const float*)d_in[5];
    const float* E   = (const float*)d_in[6];
    float* out = (float*)d_out;

    char* ws = (char*)d_ws;
    bf16* Qw   = (bf16*)(ws);                         // 4 MB  [B*L][DK]
    bf16* Kw   = (bf16*)(ws + ((size_t)4  << 20));    // 4 MB  [B*L][DK]
    bf16* Vt   = (bf16*)(ws + ((size_t)8  << 20));    // 8 MB  [D][B*L]
    bf16* SrelW= (bf16*)(ws + ((size_t)16 << 20));    // 32 MB [B,L,L] skewed
    bf16* Xq   = (bf16*)(ws + ((size_t)16 << 20));    // 8 MB  (transient)
    bf16* Xk   = (bf16*)(ws + ((size_t)24 << 20));    // 8 MB
    bf16* Xv   = (bf16*)(ws + ((size_t)32 << 20));    // 8 MB
    bf16* WqT  = (bf16*)(ws + ((size_t)48 << 20));            // [DK][D]
    bf16* WkT  = (bf16*)(ws + ((size_t)48 << 20) + 262144);   // [DK][D]
    bf16* WvT  = (bf16*)(ws + ((size_t)48 << 20) + 524288);   // [D][D]
    bf16* Eb   = (bf16*)(ws + ((size_t)49 << 20));            // [L][DK]

    conv3_f32_bf16<<<dim3(4096, 3), 256, 0, stream>>>(inQ, inK, inV, Xq, Xk, Xv,
                                                      (BB * LL * DD) / 4);
    prep_misc<<<dim3(1024, 4), 256, 0, stream>>>(E, Wq, Wk, Wv, Eb, WqT, WkT, WvT);

    // Q, K, V projections in ONE full-GPU launch (512 blocks)
    gemm_qkv<<<512, 256, 0, stream>>>(Xq, WqT, Qw, Xk, WkT, Kw, Xv, WvT, Vt);
    // Srel (skewed) = skew(Q·E^T): per-batch M=N=2048 K=256
    gemm_srel<<<dim3(16 * 16, BB), 256, 0, stream>>>(Qw, Eb, SrelW,
                                                     (long)LL * DKK, (long)LL * LL);
    attn_kernel<<<dim3(BB * 64 * 2), 256, 0, stream>>>(Qw, Kw, Vt, SrelW, out);
}